// Round 2
// baseline (752.975 us; speedup 1.0000x reference)
//
#include <hip/hip_runtime.h>
#include <math.h>

// PointWiseDecoder2DSimple on MI355X (gfx950)
// b=8, nq=nc=4096, LATENT=256, HEADS=4, DH=256, INNER=1024.
// Linear-attention decoder: all GEMMs bf16-input / fp32-MFMA-accum, all
// pointwise math fp32. Residuals carried in bf16 (error budget analysis:
// head-MLP gains ~0.3x contract residual rounding to ~3e-6 « 2.1e-5).
//
// Workspace-adaptive: the attention arm (Wkv GEMM, rot/norm/transpose,
// k^T v, q@kv, @Wo) runs in C batch-chunks, C in {1,2,4,8} picked from
// ws_size (needs 264/168/120/96 MB).

typedef unsigned short u16;
typedef __attribute__((ext_vector_type(4))) float f32x4;
typedef __attribute__((ext_vector_type(8))) short s16x8;
typedef __attribute__((ext_vector_type(8))) unsigned short u16x8;
typedef __attribute__((ext_vector_type(4))) unsigned short u16x4;

#define LOG2_1E4_D64 0.20762050593046013f  // log2(10000)/64

__device__ __forceinline__ u16 f2b(float f){
  union { float f; unsigned u; } v; v.f = f;
  unsigned u = v.u;
  u += 0x7FFFu + ((u >> 16) & 1u);
  return (u16)(u >> 16);
}
__device__ __forceinline__ float b2f(u16 b){
  union { unsigned u; float f; } v; v.u = ((unsigned)b) << 16; return v.f;
}
__device__ __forceinline__ float gelu_f(float x){
  return 0.5f * x * (1.0f + erff(x * 0.7071067811865475f));
}

// ---------------- elementwise kernels ----------------

__global__ __launch_bounds__(256) void k_cast(const float* __restrict__ in, u16* __restrict__ out){
  long i = (long)blockIdx.x * 256 + threadIdx.x;
  float4 f = ((const float4*)in)[i];
  u16x4 o = { f2b(f.x), f2b(f.y), f2b(f.z), f2b(f.w) };
  ((u16x4*)out)[i] = o;
}

// W [K][N] f32 -> Wt [N][K] bf16
__global__ __launch_bounds__(256) void k_tcast(const float* __restrict__ W, u16* __restrict__ Wt, int K, int N){
  int idx = blockIdx.x * 256 + threadIdx.x;
  int n = idx / K, k = idx - n * K;
  Wt[idx] = f2b(W[(long)k * N + n]);
}

__global__ __launch_bounds__(256) void k_fourier(const float* __restrict__ qp, const float* __restrict__ Bff, u16* __restrict__ X0){
  int tid = threadIdx.x;
  long r = (long)blockIdx.x * 2 + (tid >> 7);
  int j = tid & 127;
  float qx = qp[r*2], qy = qp[r*2+1];
  float ff = 6.283185307179586f * (qx * Bff[j] + qy * Bff[128 + j]);
  X0[r*256 + j]       = f2b(sinf(ff));
  X0[r*256 + 128 + j] = f2b(cosf(ff));
}

// in-place 2D rotary on Q (bf16). One block per row; lane j handles dims {j, j+64, j+128, j+192} of head h.
__global__ __launch_bounds__(256) void k_rot_q(u16* __restrict__ Q, const float* __restrict__ qp){
  int id = blockIdx.x * 256 + threadIdx.x;
  int l = id & 63;
  int h = (id >> 6) & 3;
  long r = (unsigned)id >> 8;
  float invf = exp2f(-(float)l * LOG2_1E4_D64);
  float ax = qp[r*2]   * 1024.0f * invf;
  float ay = qp[r*2+1] * 1024.0f * invf;
  float sx = sinf(ax), cx = cosf(ax), sy = sinf(ay), cy = cosf(ay);
  long base = r*1024 + (long)h*256 + l;
  float t0 = b2f(Q[base]), t1 = b2f(Q[base+64]), t2 = b2f(Q[base+128]), t3 = b2f(Q[base+192]);
  Q[base]       = f2b(t0*cx - t1*sx);
  Q[base + 64]  = f2b(t1*cx + t0*sx);
  Q[base + 128] = f2b(t2*cy - t3*sy);
  Q[base + 192] = f2b(t3*cy + t2*sy);
}

// K or V half: optional rotary, inst_norm over 256, transpose to [mat=(bb*4+h)][d=256][n=4096]
// in: [R rows][1024] bf16 (chunk-local rows), cp: chunk-local positions
__global__ __launch_bounds__(256) void k_kvt(const u16* __restrict__ in, const float* __restrict__ cp,
                                             u16* __restrict__ outT, int do_rot){
  __shared__ u16 sb[64*256];
  int tid  = threadIdx.x;
  int lane = tid & 63, wave = tid >> 6;
  int h = blockIdx.y;
  long n0 = (long)blockIdx.x * 64;   // chunk-local row base (64-row tiles never straddle a batch)
  int bb  = (int)(n0 >> 12);         // chunk-local batch
  int nn0 = (int)(n0 & 4095);
  float invf = exp2f(-(float)lane * LOG2_1E4_D64);

  for (int rr = 0; rr < 16; rr++){
    int lrow = wave * 16 + rr;
    long n = n0 + lrow;
    long base = n * 1024 + (long)h * 256 + lane;
    float r0 = b2f(in[base]), r1 = b2f(in[base+64]), r2 = b2f(in[base+128]), r3 = b2f(in[base+192]);
    if (do_rot){
      float ax = cp[n*2]   * 1024.0f * invf;
      float ay = cp[n*2+1] * 1024.0f * invf;
      float sx = sinf(ax), cxv = cosf(ax), sy = sinf(ay), cyv = cosf(ay);
      float t0 = r0, t1 = r1, t2 = r2, t3 = r3;
      r0 = t0*cxv - t1*sx;  r1 = t1*cxv + t0*sx;
      r2 = t2*cyv - t3*sy;  r3 = t3*cyv + t2*sy;
    }
    float s1 = r0+r1+r2+r3;
    float s2 = r0*r0+r1*r1+r2*r2+r3*r3;
#pragma unroll
    for (int m = 1; m < 64; m <<= 1){ s1 += __shfl_xor(s1, m, 64); s2 += __shfl_xor(s2, m, 64); }
    float mu  = s1 * 0.00390625f;
    float var = s2 * 0.00390625f - mu*mu;
    float inv = 1.0f / sqrtf(var + 1e-5f);
    sb[lrow*256 + lane      ] = f2b((r0-mu)*inv);
    sb[lrow*256 + lane + 64 ] = f2b((r1-mu)*inv);
    sb[lrow*256 + lane + 128] = f2b((r2-mu)*inv);
    sb[lrow*256 + lane + 192] = f2b((r3-mu)*inv);
  }
  __syncthreads();
  long ob = ((long)(bb*4 + h)*256 + tid) * 4096 + nn0;   // thread tid owns dim d=tid
  u16x8* dst = (u16x8*)(outT + ob);
#pragma unroll
  for (int c8 = 0; c8 < 8; c8++){
    u16x8 vv;
#pragma unroll
    for (int e = 0; e < 8; e++) vv[e] = sb[(c8*8+e)*256 + tid];
    dst[c8] = vv;
  }
}

// final head: out = H2 @ Wh3 + bh3  (N=3, K=128), fp32
__global__ __launch_bounds__(256) void k_final(const u16* __restrict__ H2, const float* __restrict__ Wh3,
                                               const float* __restrict__ bh3, float* __restrict__ out){
  long r = (long)blockIdx.x * 256 + threadIdx.x;
  float a0 = bh3[0], a1 = bh3[1], a2 = bh3[2];
  const u16* hrow = H2 + r*128;
#pragma unroll 4
  for (int k = 0; k < 128; k++){
    float hv = b2f(hrow[k]);
    a0 += hv * Wh3[k*3];
    a1 += hv * Wh3[k*3+1];
    a2 += hv * Wh3[k*3+2];
  }
  out[r*3] = a0; out[r*3+1] = a1; out[r*3+2] = a2;
}

// ---------------- GEMM: C = A[M,K] * B[N,K]^T, 128x128 tile, 4 waves ----------------

enum { EP_B = 0, EP_GELU = 1, EP_BIAS_GELU = 2, EP_BIAS_RESB = 3, EP_SCALE = 4, EP_T = 5, EP_QP_GELU = 6 };

struct GArgs {
  const u16* A; const u16* B;
  u16* Cb;
  const float* bias; const u16* res; const float* qp; const float* wtail;
  float scale;
  int M, N, K, lda, ldb, ldc, NLO;
  long sAh, sAl, sBh, sBl, sCh, sCl;
};

template<int EP>
__global__ __launch_bounds__(256, 2)
void gemm_k(GArgs g){
  int z = blockIdx.z;
  int zh = z / g.NLO, zl = z - zh * g.NLO;
  const u16* A = g.A + (long)zh * g.sAh + (long)zl * g.sAl;
  const u16* B = g.B + (long)zh * g.sBh + (long)zl * g.sBl;
  long coff = (long)zh * g.sCh + (long)zl * g.sCl;

  __shared__ u16 As[128*32];
  __shared__ u16 Bs[128*32];

  int tid  = threadIdx.x;
  int lane = tid & 63;
  int wave = tid >> 6;
  int wm = (wave & 1) << 6;
  int wn = (wave >> 1) << 6;
  long m0 = (long)blockIdx.x * 128;
  long n0 = (long)blockIdx.y * 128;

  int r15 = lane & 15;
  int cc  = lane >> 4;
  int fsw = (cc ^ ((r15 >> 1) & 3)) * 8;   // XOR chunk swizzle -> <=2-way LDS conflict (free, m136)

  int aoff[4], boff[4];
#pragma unroll
  for (int i = 0; i < 4; i++){
    aoff[i] = (wm + i*16 + r15) * 32 + fsw;
    boff[i] = (wn + i*16 + r15) * 32 + fsw;
  }

  int sm  = tid >> 2;
  int sc  = tid & 3;
  int so0 = sm  * 32 + ((sc ^ ((sm  >> 1) & 3)) * 8);
  int sm1 = sm + 64;
  int so1 = sm1 * 32 + ((sc ^ ((sm1 >> 1) & 3)) * 8);

  const u16* pA0 = A + (m0 + sm ) * g.lda + sc * 8;
  const u16* pA1 = A + (m0 + sm1) * g.lda + sc * 8;
  const u16* pB0 = B + (n0 + sm ) * g.ldb + sc * 8;
  const u16* pB1 = B + (n0 + sm1) * g.ldb + sc * 8;

  f32x4 acc[4][4];
#pragma unroll
  for (int i = 0; i < 4; i++)
#pragma unroll
    for (int j = 0; j < 4; j++)
      acc[i][j] = f32x4{0.f, 0.f, 0.f, 0.f};

  for (int k0 = 0; k0 < g.K; k0 += 32){
    u16x8 va0 = *(const u16x8*)(pA0 + k0);
    u16x8 va1 = *(const u16x8*)(pA1 + k0);
    u16x8 vb0 = *(const u16x8*)(pB0 + k0);
    u16x8 vb1 = *(const u16x8*)(pB1 + k0);
    __syncthreads();
    *(u16x8*)&As[so0] = va0;
    *(u16x8*)&As[so1] = va1;
    *(u16x8*)&Bs[so0] = vb0;
    *(u16x8*)&Bs[so1] = vb1;
    __syncthreads();
    s16x8 af[4], bf[4];
#pragma unroll
    for (int i = 0; i < 4; i++) af[i] = *(const s16x8*)&As[aoff[i]];
#pragma unroll
    for (int i = 0; i < 4; i++) bf[i] = *(const s16x8*)&Bs[boff[i]];
#pragma unroll
    for (int i = 0; i < 4; i++)
#pragma unroll
      for (int j = 0; j < 4; j++)
        acc[i][j] = __builtin_amdgcn_mfma_f32_16x16x32_bf16(af[i], bf[j], acc[i][j], 0, 0, 0);
  }

  int colb = (int)n0 + wn + r15;
  int rowb = (int)m0 + wm + cc * 4;
#pragma unroll
  for (int i = 0; i < 4; i++){
#pragma unroll
    for (int j = 0; j < 4; j++){
      int col = colb + j*16;
#pragma unroll
      for (int r = 0; r < 4; r++){
        int row = rowb + i*16 + r;
        float v = acc[i][j][r];
        if constexpr (EP == EP_B){
          g.Cb[coff + (long)row * g.ldc + col] = f2b(v);
        } else if constexpr (EP == EP_GELU){
          g.Cb[coff + (long)row * g.ldc + col] = f2b(gelu_f(v));
        } else if constexpr (EP == EP_BIAS_GELU){
          v = gelu_f(v + g.bias[col]);
          g.Cb[coff + (long)row * g.ldc + col] = f2b(v);
        } else if constexpr (EP == EP_BIAS_RESB){
          v += g.bias[col] + b2f(g.res[(long)row * g.ldc + col]);
          g.Cb[coff + (long)row * g.ldc + col] = f2b(v);
        } else if constexpr (EP == EP_SCALE){
          g.Cb[coff + (long)row * g.ldc + col] = f2b(v * g.scale);
        } else if constexpr (EP == EP_T){
          g.Cb[coff + (long)col * g.ldc + row] = f2b(v);
        } else { // EP_QP_GELU: rank-2 update for [x, query_pos] concat (Wh1 rows 256,257)
          v += g.qp[(long)row*2] * g.wtail[col] + g.qp[(long)row*2+1] * g.wtail[256+col];
          g.Cb[coff + (long)row * g.ldc + col] = f2b(gelu_f(v));
        }
      }
    }
  }
}

// ---------------- host ----------------

extern "C" void kernel_launch(void* const* d_in, const int* in_sizes, int n_in,
                              void* d_out, int out_size, void* d_ws, size_t ws_size,
                              hipStream_t stream){
  const float* z   = (const float*)d_in[0];
  const float* qp  = (const float*)d_in[1];
  const float* cp  = (const float*)d_in[2];
  const float* Bff = (const float*)d_in[3];
  const float* Wc1 = (const float*)d_in[4];
  const float* Wc2 = (const float*)d_in[5];
  const float* Wq  = (const float*)d_in[6];
  const float* Wkv = (const float*)d_in[7];
  const float* Wo  = (const float*)d_in[8];
  const float* bo  = (const float*)d_in[9];
  const float* Wf1 = (const float*)d_in[10];
  const float* bf1 = (const float*)d_in[11];
  const float* Wf2 = (const float*)d_in[12];
  const float* bf2 = (const float*)d_in[13];
  const float* Wh1 = (const float*)d_in[14];
  const float* Wh2 = (const float*)d_in[15];
  const float* Wh3 = (const float*)d_in[16];
  const float* bh3 = (const float*)d_in[17];
  float* out = (float*)d_out;
  (void)in_sizes; (void)n_in; (void)out_size;

  // ---- chunking: C batch-chunks of NB=8/C batches; ws need = 72 + 24*NB MB
  size_t mb = ws_size >> 20;
  int C;
  if      (mb >= 264) C = 1;
  else if (mb >= 168) C = 2;
  else if (mb >= 120) C = 4;
  else                C = 8;
  const int NB = 8 / C;
  const long R = (long)NB * 4096;         // rows per chunk

  char* ws = (char*)d_ws;
  const size_t MB = 1024*1024;
  // weights (bf16, transposed) in [0, 4MB)
  u16* WqT  = (u16*)(ws + 0);             // 512KB
  u16* WkvT = (u16*)(ws + 512*1024);      // 1MB
  u16* WoT  = (u16*)(ws + 1536*1024);     // 512KB
  u16* Wc1T = (u16*)(ws + 2048*1024);
  u16* Wc2T = (u16*)(ws + (2048+128)*1024);
  u16* Wf1T = (u16*)(ws + (2048+256)*1024);
  u16* Wf2T = (u16*)(ws + (2048+384)*1024);
  u16* Wh1T = (u16*)(ws + (2048+512)*1024);
  u16* Wh2T = (u16*)(ws + (2048+640)*1024);
  // full-size regions (16MB each)
  u16* R1 = (u16*)(ws + 4*MB);    // X0b -> X2b
  u16* R2 = (u16*)(ws + 20*MB);   // Tb -> T2 -> H1b
  u16* R3 = (u16*)(ws + 36*MB);   // Xb -> X3
  u16* R4 = (u16*)(ws + 52*MB);   // Zb -> H2b
  u16* kvT = (u16*)(ws + 68*MB);  // 4MB: 32 mats of [e=256][d=256]
  // chunk buffers (NB*8MB each)
  u16* BIG1 = (u16*)(ws + 72*MB);                     // Kb -> Vb -> Qb
  u16* BIG2 = (u16*)((char*)BIG1 + (size_t)NB*8*MB);  // Kt -> ATTb
  u16* BIG3 = (u16*)((char*)BIG2 + (size_t)NB*8*MB);  // Vt

  u16* X0b = R1; u16* X2b = R1;
  u16* Tb  = R2; u16* H1b = R2;
  u16* Xb  = R3;                    // x residual (live through G7), then X3
  u16* Zb  = R4; u16* H2b = R4;

  auto G = [&](int ep, const u16* A, const u16* B, u16* Cb,
               const float* bias, const u16* res, const float* qq, const float* wtail,
               float scale, int M, int N, int K, int lda, int ldb, int ldc,
               int nz, int NLO, long sAh, long sAl, long sBh, long sBl, long sCh, long sCl){
    GArgs g;
    g.A=A; g.B=B; g.Cb=Cb; g.bias=bias; g.res=res; g.qp=qq; g.wtail=wtail;
    g.scale=scale; g.M=M; g.N=N; g.K=K; g.lda=lda; g.ldb=ldb; g.ldc=ldc; g.NLO=NLO;
    g.sAh=sAh; g.sAl=sAl; g.sBh=sBh; g.sBl=sBl; g.sCh=sCh; g.sCl=sCl;
    dim3 gr(M/128, N/128, nz); dim3 bl(256);
    switch(ep){
      case EP_B:          gemm_k<EP_B><<<gr,bl,0,stream>>>(g); break;
      case EP_GELU:       gemm_k<EP_GELU><<<gr,bl,0,stream>>>(g); break;
      case EP_BIAS_GELU:  gemm_k<EP_BIAS_GELU><<<gr,bl,0,stream>>>(g); break;
      case EP_BIAS_RESB:  gemm_k<EP_BIAS_RESB><<<gr,bl,0,stream>>>(g); break;
      case EP_SCALE:      gemm_k<EP_SCALE><<<gr,bl,0,stream>>>(g); break;
      case EP_T:          gemm_k<EP_T><<<gr,bl,0,stream>>>(g); break;
      case EP_QP_GELU:    gemm_k<EP_QP_GELU><<<gr,bl,0,stream>>>(g); break;
    }
  };

  // ---- weight prep + z cast
  k_cast<<<dim3(8192), dim3(256), 0, stream>>>(z, Zb);
  k_tcast<<<dim3(1024), dim3(256), 0, stream>>>(Wq,  WqT,  256, 1024);
  k_tcast<<<dim3(2048), dim3(256), 0, stream>>>(Wkv, WkvT, 256, 2048);
  k_tcast<<<dim3(1024), dim3(256), 0, stream>>>(Wo,  WoT,  1024, 256);
  k_tcast<<<dim3(256),  dim3(256), 0, stream>>>(Wc1, Wc1T, 256, 256);
  k_tcast<<<dim3(256),  dim3(256), 0, stream>>>(Wc2, Wc2T, 256, 256);
  k_tcast<<<dim3(256),  dim3(256), 0, stream>>>(Wf1, Wf1T, 256, 256);
  k_tcast<<<dim3(256),  dim3(256), 0, stream>>>(Wf2, Wf2T, 256, 256);
  k_tcast<<<dim3(256),  dim3(256), 0, stream>>>(Wh1, Wh1T, 256, 256);  // rows 0..255
  k_tcast<<<dim3(128),  dim3(256), 0, stream>>>(Wh2, Wh2T, 256, 128);

  // ---- query trunk: fourier -> gelu(@Wc1) -> @Wc2 = x
  k_fourier<<<dim3(16384), dim3(256), 0, stream>>>(qp, Bff, X0b);
  G(EP_GELU, X0b, Wc1T, Tb, 0,0,0,0, 1.f, 32768,256,256, 256,256,256, 1,1, 0,0,0,0,0,0);
  G(EP_B,    Tb,  Wc2T, Xb, 0,0,0,0, 1.f, 32768,256,256, 256,256,256, 1,1, 0,0,0,0,0,0);

  // ---- attention arm, per batch-chunk
  for (int c = 0; c < C; c++){
    long row0 = (long)c * R;
    const u16* Zc = Zb + row0 * 256;
    // K half: z@Wkv[:,0:1024] -> rot+norm+transpose -> Kt
    G(EP_B, Zc, WkvT, BIG1, 0,0,0,0, 1.f, (int)R,1024,256, 256,256,1024, 1,1, 0,0,0,0,0,0);
    k_kvt<<<dim3((int)(R/64), 4), dim3(256), 0, stream>>>(BIG1, cp + row0*2, BIG2, 1);
    // V half: z@Wkv[:,1024:2048] -> norm+transpose -> Vt
    G(EP_B, Zc, WkvT + 1024*256, BIG1, 0,0,0,0, 1.f, (int)R,1024,256, 256,256,1024, 1,1, 0,0,0,0,0,0);
    k_kvt<<<dim3((int)(R/64), 4), dim3(256), 0, stream>>>(BIG1, cp + row0*2, BIG3, 0);
    // kv^T = (k^T v)^T per (b,h):  [e][d]
    G(EP_T, BIG2, BIG3, kvT + (long)c*NB*262144, 0,0,0,0, 1.f,
      256,256,4096, 4096,4096,256, NB*4,1, 1048576,0, 1048576,0, 65536,0);
    // Q = x@Wq, rotary
    G(EP_B, Xb + row0*256, WqT, BIG1, 0,0,0,0, 1.f, (int)R,1024,256, 256,256,1024, 1,1, 0,0,0,0,0,0);
    k_rot_q<<<dim3((int)R), dim3(256), 0, stream>>>(BIG1, qp + row0*2);
    // attn = q@kv * (1/nc)  -> [n][h*256+e]
    G(EP_SCALE, BIG1, kvT + (long)c*NB*262144, BIG2, 0,0,0,0, 1.0f/4096.0f,
      4096,256,256, 1024,256,1024, NB*4,4, 4194304,256, 262144,65536, 4194304,256);
    // x2 = attn@Wo + bo + x
    G(EP_BIAS_RESB, BIG2, WoT, X2b + row0*256, bo, Xb + row0*256, 0,0, 1.f,
      (int)R,256,1024, 1024,1024,256, 1,1, 0,0,0,0,0,0);
  }

  // ---- FF block + head MLP (full 32768 rows)
  G(EP_BIAS_GELU, X2b, Wf1T, Tb, bf1, 0,0,0, 1.f, 32768,256,256, 256,256,256, 1,1, 0,0,0,0,0,0);
  G(EP_BIAS_RESB, Tb, Wf2T, Xb, bf2, X2b, 0,0, 1.f, 32768,256,256, 256,256,256, 1,1, 0,0,0,0,0,0); // X3 -> R3
  G(EP_QP_GELU, Xb, Wh1T, H1b, 0,0, qp, Wh1 + 65536, 1.f, 32768,256,256, 256,256,256, 1,1, 0,0,0,0,0,0);
  G(EP_GELU, H1b, Wh2T, H2b, 0,0,0,0, 1.f, 32768,128,256, 256,256,128, 1,1, 0,0,0,0,0,0);
  k_final<<<dim3(128), dim3(256), 0, stream>>>(H2b, Wh3, bh3, out);
}

// Round 3
// 648.192 us; speedup vs baseline: 1.1617x; 1.1617x over previous
//
#include <hip/hip_runtime.h>
#include <math.h>

// PointWiseDecoder2DSimple on MI355X (gfx950)
// b=8, nq=nc=4096, LATENT=256, HEADS=4, DH=256, INNER=1024.
// Linear-attention decoder: GEMMs bf16-input / fp32-MFMA-accum, pointwise fp32.
// R3 changes: coalesced k_kvt transpose, global_load_lds GEMM staging (m97),
// split-K(4) for the k^T v contraction, fused weight-transpose launches.

typedef unsigned short u16;
typedef __attribute__((ext_vector_type(4))) float f32x4;
typedef __attribute__((ext_vector_type(8))) short s16x8;
typedef __attribute__((ext_vector_type(8))) unsigned short u16x8;
typedef __attribute__((ext_vector_type(4))) unsigned short u16x4;

#define LOG2_1E4_D64 0.20762050593046013f  // log2(10000)/64

__device__ __forceinline__ u16 f2b(float f){
  union { float f; unsigned u; } v; v.f = f;
  unsigned u = v.u;
  u += 0x7FFFu + ((u >> 16) & 1u);
  return (u16)(u >> 16);
}
__device__ __forceinline__ float b2f(u16 b){
  union { unsigned u; float f; } v; v.u = ((unsigned)b) << 16; return v.f;
}
__device__ __forceinline__ float gelu_f(float x){
  return 0.5f * x * (1.0f + erff(x * 0.7071067811865475f));
}

#if __has_builtin(__builtin_amdgcn_global_load_lds)
#define HAVE_GLL 1
typedef const __attribute__((address_space(1))) void* as1cv;
typedef __attribute__((address_space(3))) void* as3v;
__device__ __forceinline__ void gload16(const void* g, void* l){
  __builtin_amdgcn_global_load_lds((as1cv)g, (as3v)l, 16, 0, 0);
}
#else
#define HAVE_GLL 0
#endif

// ---------------- elementwise kernels ----------------

__global__ __launch_bounds__(256) void k_cast(const float* __restrict__ in, u16* __restrict__ out){
  long i = (long)blockIdx.x * 256 + threadIdx.x;
  float4 f = ((const float4*)in)[i];
  u16x4 o = { f2b(f.x), f2b(f.y), f2b(f.z), f2b(f.w) };
  ((u16x4*)out)[i] = o;
}

// all 9 weight transposes (f32 [K][N] -> bf16 [N][K]) in one launch
struct TCArgs {
  const float* W[9]; u16* Wt[9];
  int K[9]; int N[9]; int boff[10];
};
__global__ __launch_bounds__(256) void k_tcast_all(TCArgs a){
  int b = blockIdx.x;
  int w = 0;
  while (b >= a.boff[w+1]) w++;
  int idx = (b - a.boff[w]) * 256 + threadIdx.x;
  int K = a.K[w], N = a.N[w];
  int n = idx / K, k = idx - n * K;
  a.Wt[w][idx] = f2b(a.W[w][(long)k * N + n]);
}

__global__ __launch_bounds__(256) void k_fourier(const float* __restrict__ qp, const float* __restrict__ Bff, u16* __restrict__ X0){
  int tid = threadIdx.x;
  long r = (long)blockIdx.x * 2 + (tid >> 7);
  int j = tid & 127;
  float qx = qp[r*2], qy = qp[r*2+1];
  float ff = 6.283185307179586f * (qx * Bff[j] + qy * Bff[128 + j]);
  X0[r*256 + j]       = f2b(sinf(ff));
  X0[r*256 + 128 + j] = f2b(cosf(ff));
}

// in-place 2D rotary on Q (bf16). lane j handles dims {j, j+64, j+128, j+192} of head h.
__global__ __launch_bounds__(256) void k_rot_q(u16* __restrict__ Q, const float* __restrict__ qp){
  int id = blockIdx.x * 256 + threadIdx.x;
  int l = id & 63;
  int h = (id >> 6) & 3;
  long r = (unsigned)id >> 8;
  float invf = exp2f(-(float)l * LOG2_1E4_D64);
  float ax = qp[r*2]   * 1024.0f * invf;
  float ay = qp[r*2+1] * 1024.0f * invf;
  float sx = sinf(ax), cx = cosf(ax), sy = sinf(ay), cy = cosf(ay);
  long base = r*1024 + (long)h*256 + l;
  float t0 = b2f(Q[base]), t1 = b2f(Q[base+64]), t2 = b2f(Q[base+128]), t3 = b2f(Q[base+192]);
  Q[base]       = f2b(t0*cx - t1*sx);
  Q[base + 64]  = f2b(t1*cx + t0*sx);
  Q[base + 128] = f2b(t2*cy - t3*sy);
  Q[base + 192] = f2b(t3*cy + t2*sy);
}

// K or V half: optional rotary, inst_norm over 256, transpose to [mat][d=256][n]
// Coalesced write-out: wave covers 4 d-rows x 64 consecutive n (u16x4 stores).
// LDS swizzle d ^ ((n>>2)<<1): phase-1 writes 2-way max, phase-2 reads 2-way max (free).
__global__ __launch_bounds__(256) void k_kvt(const u16* __restrict__ in, const float* __restrict__ cp,
                                             u16* __restrict__ outT, int do_rot){
  __shared__ u16 sb[64*256];
  int tid  = threadIdx.x;
  int lane = tid & 63, wave = tid >> 6;
  int h = blockIdx.y;
  long n0 = (long)blockIdx.x * 64;
  int bb  = (int)(n0 >> 12);
  int nn0 = (int)(n0 & 4095);
  float invf = exp2f(-(float)lane * LOG2_1E4_D64);

  for (int rr = 0; rr < 16; rr++){
    int lrow = wave * 16 + rr;
    long n = n0 + lrow;
    long base = n * 1024 + (long)h * 256 + lane;
    float r0 = b2f(in[base]), r1 = b2f(in[base+64]), r2 = b2f(in[base+128]), r3 = b2f(in[base+192]);
    if (do_rot){
      float ax = cp[n*2]   * 1024.0f * invf;
      float ay = cp[n*2+1] * 1024.0f * invf;
      float sx = sinf(ax), cxv = cosf(ax), sy = sinf(ay), cyv = cosf(ay);
      float t0 = r0, t1 = r1, t2 = r2, t3 = r3;
      r0 = t0*cxv - t1*sx;  r1 = t1*cxv + t0*sx;
      r2 = t2*cyv - t3*sy;  r3 = t3*cyv + t2*sy;
    }
    float s1 = r0+r1+r2+r3;
    float s2 = r0*r0+r1*r1+r2*r2+r3*r3;
#pragma unroll
    for (int m = 1; m < 64; m <<= 1){ s1 += __shfl_xor(s1, m, 64); s2 += __shfl_xor(s2, m, 64); }
    float mu  = s1 * 0.00390625f;
    float var = s2 * 0.00390625f - mu*mu;
    float inv = 1.0f / sqrtf(var + 1e-5f);
    int sw = (lrow >> 2) << 1;
    sb[lrow*256 + ((lane      ) ^ sw)] = f2b((r0-mu)*inv);
    sb[lrow*256 + ((lane + 64 ) ^ sw)] = f2b((r1-mu)*inv);
    sb[lrow*256 + ((lane + 128) ^ sw)] = f2b((r2-mu)*inv);
    sb[lrow*256 + ((lane + 192) ^ sw)] = f2b((r3-mu)*inv);
  }
  __syncthreads();
  long matbase = ((long)(bb*4 + h) * 256) * 4096 + nn0;
  int n4 = (lane & 15) * 4;
  int sw = (lane & 15) << 1;       // = ((n4>>2)&31)<<1, uniform over j<4
#pragma unroll
  for (int rnd = 0; rnd < 16; rnd++){
    int d = rnd*16 + wave*4 + (lane >> 4);
    u16x4 vv;
#pragma unroll
    for (int j = 0; j < 4; j++) vv[j] = sb[(n4+j)*256 + (d ^ sw)];
    *(u16x4*)(outT + matbase + (long)d*4096 + n4) = vv;
  }
}

// split-K reduce: kvT[i] = bf16(sum_sp p[sp][i]), SPL=4
__global__ __launch_bounds__(256) void k_red(const float* __restrict__ p, u16* __restrict__ out, long stride){
  long i = (long)blockIdx.x * 256 + threadIdx.x;
  f32x4 s = ((const f32x4*)p)[i];
  s += ((const f32x4*)(p + stride))[i];
  s += ((const f32x4*)(p + 2*stride))[i];
  s += ((const f32x4*)(p + 3*stride))[i];
  u16x4 o = { f2b(s[0]), f2b(s[1]), f2b(s[2]), f2b(s[3]) };
  ((u16x4*)out)[i] = o;
}

// final head: out = H2 @ Wh3 + bh3  (N=3, K=128), fp32
__global__ __launch_bounds__(256) void k_final(const u16* __restrict__ H2, const float* __restrict__ Wh3,
                                               const float* __restrict__ bh3, float* __restrict__ out){
  long r = (long)blockIdx.x * 256 + threadIdx.x;
  float a0 = bh3[0], a1 = bh3[1], a2 = bh3[2];
  const u16x8* hrow = (const u16x8*)(H2 + r*128);
#pragma unroll
  for (int c8 = 0; c8 < 16; c8++){
    u16x8 hv = hrow[c8];
#pragma unroll
    for (int e = 0; e < 8; e++){
      float f = b2f(hv[e]);
      int k = c8*8 + e;
      a0 += f * Wh3[k*3];
      a1 += f * Wh3[k*3+1];
      a2 += f * Wh3[k*3+2];
    }
  }
  out[r*3] = a0; out[r*3+1] = a1; out[r*3+2] = a2;
}

// ---------------- GEMM: C = A[M,K] * B[N,K]^T, 128x128 tile, 4 waves ----------------
// Staging: global_load_lds width=16 (m97 pattern), linear LDS [128][32].

enum { EP_B = 0, EP_GELU = 1, EP_BIAS_GELU = 2, EP_BIAS_RESB = 3, EP_SCALE = 4,
       EP_T = 5, EP_QP_GELU = 6, EP_TF32 = 7 };

struct GArgs {
  const u16* A; const u16* B;
  u16* Cb; float* Cf;
  const float* bias; const u16* res; const float* qp; const float* wtail;
  float scale;
  int M, N, K, lda, ldb, ldc, NLO;
  long sAh, sAl, sBh, sBl, sCh, sCl;
};

template<int EP>
__global__ __launch_bounds__(256, 2)
void gemm_k(GArgs g){
  int z = blockIdx.z;
  int zh = z / g.NLO, zl = z - zh * g.NLO;
  const u16* A = g.A + (long)zh * g.sAh + (long)zl * g.sAl;
  const u16* B = g.B + (long)zh * g.sBh + (long)zl * g.sBl;
  long coff = (long)zh * g.sCh + (long)zl * g.sCl;

  __shared__ u16 As[128*32];
  __shared__ u16 Bs[128*32];

  int tid  = threadIdx.x;
  int lane = tid & 63;
  int wave = tid >> 6;
  int wm = (wave & 1) << 6;
  int wn = (wave >> 1) << 6;
  long m0 = (long)blockIdx.x * 128;
  long n0 = (long)blockIdx.y * 128;

  int r15 = lane & 15;
  int cc  = lane >> 4;

#if HAVE_GLL
  // wave w, instr i in {0,1}: LDS rows (w*2+i)*16, lane l -> row +l/4, col (l&3)*8
  int rA0 = (wave*2 + 0) * 16;
  int rA1 = (wave*2 + 1) * 16;
  int srow = lane >> 2;
  int scol = (lane & 3) * 8;
  u16* lA0 = &As[rA0*32];
  u16* lA1 = &As[rA1*32];
  u16* lB0 = &Bs[rA0*32];
  u16* lB1 = &Bs[rA1*32];
  const u16* gA0 = A + (m0 + rA0 + srow) * g.lda + scol;
  const u16* gA1 = A + (m0 + rA1 + srow) * g.lda + scol;
  const u16* gB0 = B + (n0 + rA0 + srow) * g.ldb + scol;
  const u16* gB1 = B + (n0 + rA1 + srow) * g.ldb + scol;
#else
  int sm  = tid >> 2;
  int sc  = tid & 3;
  int so0 = sm * 32 + sc * 8;
  int so1 = (sm + 64) * 32 + sc * 8;
  const u16* pA0 = A + (m0 + sm ) * g.lda + sc * 8;
  const u16* pA1 = A + (m0 + sm + 64) * g.lda + sc * 8;
  const u16* pB0 = B + (n0 + sm ) * g.ldb + sc * 8;
  const u16* pB1 = B + (n0 + sm + 64) * g.ldb + sc * 8;
#endif

  f32x4 acc[4][4];
#pragma unroll
  for (int i = 0; i < 4; i++)
#pragma unroll
    for (int j = 0; j < 4; j++)
      acc[i][j] = f32x4{0.f, 0.f, 0.f, 0.f};

  for (int k0 = 0; k0 < g.K; k0 += 32){
#if HAVE_GLL
    __syncthreads();
    gload16(gA0 + k0, lA0);
    gload16(gA1 + k0, lA1);
    gload16(gB0 + k0, lB0);
    gload16(gB1 + k0, lB1);
    __syncthreads();
#else
    u16x8 va0 = *(const u16x8*)(pA0 + k0);
    u16x8 va1 = *(const u16x8*)(pA1 + k0);
    u16x8 vb0 = *(const u16x8*)(pB0 + k0);
    u16x8 vb1 = *(const u16x8*)(pB1 + k0);
    __syncthreads();
    *(u16x8*)&As[so0] = va0;
    *(u16x8*)&As[so1] = va1;
    *(u16x8*)&Bs[so0] = vb0;
    *(u16x8*)&Bs[so1] = vb1;
    __syncthreads();
#endif
    s16x8 af[4], bf[4];
#pragma unroll
    for (int i = 0; i < 4; i++) af[i] = *(const s16x8*)&As[(wm + i*16 + r15)*32 + cc*8];
#pragma unroll
    for (int i = 0; i < 4; i++) bf[i] = *(const s16x8*)&Bs[(wn + i*16 + r15)*32 + cc*8];
#pragma unroll
    for (int i = 0; i < 4; i++)
#pragma unroll
      for (int j = 0; j < 4; j++)
        acc[i][j] = __builtin_amdgcn_mfma_f32_16x16x32_bf16(af[i], bf[j], acc[i][j], 0, 0, 0);
  }

  int colb = (int)n0 + wn + r15;
  int rowb = (int)m0 + wm + cc * 4;
#pragma unroll
  for (int i = 0; i < 4; i++){
#pragma unroll
    for (int j = 0; j < 4; j++){
      int col = colb + j*16;
#pragma unroll
      for (int r = 0; r < 4; r++){
        int row = rowb + i*16 + r;
        float v = acc[i][j][r];
        if constexpr (EP == EP_B){
          g.Cb[coff + (long)row * g.ldc + col] = f2b(v);
        } else if constexpr (EP == EP_GELU){
          g.Cb[coff + (long)row * g.ldc + col] = f2b(gelu_f(v));
        } else if constexpr (EP == EP_BIAS_GELU){
          v = gelu_f(v + g.bias[col]);
          g.Cb[coff + (long)row * g.ldc + col] = f2b(v);
        } else if constexpr (EP == EP_BIAS_RESB){
          v += g.bias[col] + b2f(g.res[(long)row * g.ldc + col]);
          g.Cb[coff + (long)row * g.ldc + col] = f2b(v);
        } else if constexpr (EP == EP_SCALE){
          g.Cb[coff + (long)row * g.ldc + col] = f2b(v * g.scale);
        } else if constexpr (EP == EP_T){
          g.Cb[coff + (long)col * g.ldc + row] = f2b(v);
        } else if constexpr (EP == EP_TF32){
          g.Cf[coff + (long)col * g.ldc + row] = v;
        } else { // EP_QP_GELU: rank-2 update for [x, query_pos] concat (Wh1 rows 256,257)
          v += g.qp[(long)row*2] * g.wtail[col] + g.qp[(long)row*2+1] * g.wtail[256+col];
          g.Cb[coff + (long)row * g.ldc + col] = f2b(gelu_f(v));
        }
      }
    }
  }
}

// ---------------- host ----------------

extern "C" void kernel_launch(void* const* d_in, const int* in_sizes, int n_in,
                              void* d_out, int out_size, void* d_ws, size_t ws_size,
                              hipStream_t stream){
  const float* z   = (const float*)d_in[0];
  const float* qp  = (const float*)d_in[1];
  const float* cp  = (const float*)d_in[2];
  const float* Bff = (const float*)d_in[3];
  const float* Wc1 = (const float*)d_in[4];
  const float* Wc2 = (const float*)d_in[5];
  const float* Wq  = (const float*)d_in[6];
  const float* Wkv = (const float*)d_in[7];
  const float* Wo  = (const float*)d_in[8];
  const float* bo  = (const float*)d_in[9];
  const float* Wf1 = (const float*)d_in[10];
  const float* bf1 = (const float*)d_in[11];
  const float* Wf2 = (const float*)d_in[12];
  const float* bf2 = (const float*)d_in[13];
  const float* Wh1 = (const float*)d_in[14];
  const float* Wh2 = (const float*)d_in[15];
  const float* Wh3 = (const float*)d_in[16];
  const float* bh3 = (const float*)d_in[17];
  float* out = (float*)d_out;
  (void)in_sizes; (void)n_in; (void)out_size;

  size_t mb = ws_size >> 20;
  int C;
  if      (mb >= 264) C = 1;
  else if (mb >= 168) C = 2;
  else if (mb >= 120) C = 4;
  else                C = 8;
  const int NB = 8 / C;
  const long R = (long)NB * 4096;

  char* ws = (char*)d_ws;
  const size_t MB = 1024*1024;
  u16* WqT  = (u16*)(ws + 0);
  u16* WkvT = (u16*)(ws + 512*1024);
  u16* WoT  = (u16*)(ws + 1536*1024);
  u16* Wc1T = (u16*)(ws + 2048*1024);
  u16* Wc2T = (u16*)(ws + (2048+128)*1024);
  u16* Wf1T = (u16*)(ws + (2048+256)*1024);
  u16* Wf2T = (u16*)(ws + (2048+384)*1024);
  u16* Wh1T = (u16*)(ws + (2048+512)*1024);
  u16* Wh2T = (u16*)(ws + (2048+640)*1024);
  u16* R1 = (u16*)(ws + 4*MB);    // X0b -> X2b
  u16* R2 = (u16*)(ws + 20*MB);   // Tb -> H1b
  u16* R3 = (u16*)(ws + 36*MB);   // Xb -> X3
  u16* R4 = (u16*)(ws + 52*MB);   // Zb -> H2b
  u16* kvT = (u16*)(ws + 68*MB);  // 4MB: 32 mats [e=256][d=256]
  u16* BIG1 = (u16*)(ws + 72*MB);                     // Kb/Vb -> f32 kv partials -> Qb
  u16* BIG2 = (u16*)((char*)BIG1 + (size_t)NB*8*MB);  // Kt -> ATTb
  u16* BIG3 = (u16*)((char*)BIG2 + (size_t)NB*8*MB);  // Vt

  u16* X0b = R1; u16* X2b = R1;
  u16* Tb  = R2; u16* H1b = R2;
  u16* Xb  = R3;
  u16* Zb  = R4; u16* H2b = R4;

  auto G = [&](int ep, const u16* A, const u16* B, u16* Cb, float* Cf,
               const float* bias, const u16* res, const float* qq, const float* wtail,
               float scale, int M, int N, int K, int lda, int ldb, int ldc,
               int nz, int NLO, long sAh, long sAl, long sBh, long sBl, long sCh, long sCl){
    GArgs g;
    g.A=A; g.B=B; g.Cb=Cb; g.Cf=Cf; g.bias=bias; g.res=res; g.qp=qq; g.wtail=wtail;
    g.scale=scale; g.M=M; g.N=N; g.K=K; g.lda=lda; g.ldb=ldb; g.ldc=ldc; g.NLO=NLO;
    g.sAh=sAh; g.sAl=sAl; g.sBh=sBh; g.sBl=sBl; g.sCh=sCh; g.sCl=sCl;
    dim3 gr(M/128, N/128, nz); dim3 bl(256);
    switch(ep){
      case EP_B:          gemm_k<EP_B><<<gr,bl,0,stream>>>(g); break;
      case EP_GELU:       gemm_k<EP_GELU><<<gr,bl,0,stream>>>(g); break;
      case EP_BIAS_GELU:  gemm_k<EP_BIAS_GELU><<<gr,bl,0,stream>>>(g); break;
      case EP_BIAS_RESB:  gemm_k<EP_BIAS_RESB><<<gr,bl,0,stream>>>(g); break;
      case EP_SCALE:      gemm_k<EP_SCALE><<<gr,bl,0,stream>>>(g); break;
      case EP_T:          gemm_k<EP_T><<<gr,bl,0,stream>>>(g); break;
      case EP_QP_GELU:    gemm_k<EP_QP_GELU><<<gr,bl,0,stream>>>(g); break;
      case EP_TF32:       gemm_k<EP_TF32><<<gr,bl,0,stream>>>(g); break;
    }
  };

  // ---- weight prep + z cast (one tcast launch)
  k_cast<<<dim3(8192), dim3(256), 0, stream>>>(z, Zb);
  {
    TCArgs a;
    const float* Ws[9] = { Wq, Wkv, Wo, Wc1, Wc2, Wf1, Wf2, Wh1, Wh2 };
    u16* Wts[9] = { WqT, WkvT, WoT, Wc1T, Wc2T, Wf1T, Wf2T, Wh1T, Wh2T };
    int Ks[9] = { 256, 256, 1024, 256, 256, 256, 256, 256, 256 };
    int Ns[9] = { 1024, 2048, 256, 256, 256, 256, 256, 256, 128 };
    int off = 0;
    for (int i = 0; i < 9; i++){
      a.W[i] = Ws[i]; a.Wt[i] = Wts[i]; a.K[i] = Ks[i]; a.N[i] = Ns[i];
      a.boff[i] = off; off += Ks[i]*Ns[i]/256;
    }
    a.boff[9] = off;
    k_tcast_all<<<dim3(off), dim3(256), 0, stream>>>(a);
  }

  // ---- query trunk
  k_fourier<<<dim3(16384), dim3(256), 0, stream>>>(qp, Bff, X0b);
  G(EP_GELU, X0b, Wc1T, Tb, 0, 0,0,0,0, 1.f, 32768,256,256, 256,256,256, 1,1, 0,0,0,0,0,0);
  G(EP_B,    Tb,  Wc2T, Xb, 0, 0,0,0,0, 1.f, 32768,256,256, 256,256,256, 1,1, 0,0,0,0,0,0);

  // ---- attention arm, per batch-chunk
  for (int c = 0; c < C; c++){
    long row0 = (long)c * R;
    const u16* Zc = Zb + row0 * 256;
    // K half -> rot+norm+transpose
    G(EP_B, Zc, WkvT, BIG1, 0, 0,0,0,0, 1.f, (int)R,1024,256, 256,256,1024, 1,1, 0,0,0,0,0,0);
    k_kvt<<<dim3((int)(R/64), 4), dim3(256), 0, stream>>>(BIG1, cp + row0*2, BIG2, 1);
    // V half -> norm+transpose
    G(EP_B, Zc, WkvT + 1024*256, BIG1, 0, 0,0,0,0, 1.f, (int)R,1024,256, 256,256,1024, 1,1, 0,0,0,0,0,0);
    k_kvt<<<dim3((int)(R/64), 4), dim3(256), 0, stream>>>(BIG1, cp + row0*2, BIG3, 0);
    // kv^T = (k^T v)^T per mat, split-K 4: f32 partials [sp][mat][e][d] in BIG1, then reduce
    G(EP_TF32, BIG2, BIG3, 0, (float*)BIG1, 0,0,0,0, 1.f,
      256,256,1024, 4096,4096,256, 4*NB*4, NB*4,
      1024,1048576, 1024,1048576, (long)NB*4*65536,65536);
    k_red<<<dim3(NB*256), dim3(256), 0, stream>>>((float*)BIG1, kvT + (long)c*NB*4*65536, (long)NB*4*65536);
    // Q = x@Wq, rotary
    G(EP_B, Xb + row0*256, WqT, BIG1, 0, 0,0,0,0, 1.f, (int)R,1024,256, 256,256,1024, 1,1, 0,0,0,0,0,0);
    k_rot_q<<<dim3((int)R), dim3(256), 0, stream>>>(BIG1, qp + row0*2);
    // attn = q@kv * (1/nc)
    G(EP_SCALE, BIG1, kvT + (long)c*NB*4*65536, BIG2, 0, 0,0,0,0, 1.0f/4096.0f,
      4096,256,256, 1024,256,1024, NB*4,4, 4194304,256, 262144,65536, 4194304,256);
    // x2 = attn@Wo + bo + x
    G(EP_BIAS_RESB, BIG2, WoT, X2b + row0*256, 0, bo, Xb + row0*256, 0,0, 1.f,
      (int)R,256,1024, 1024,1024,256, 1,1, 0,0,0,0,0,0);
  }

  // ---- FF block + head MLP
  G(EP_BIAS_GELU, X2b, Wf1T, Tb, 0, bf1, 0,0,0, 1.f, 32768,256,256, 256,256,256, 1,1, 0,0,0,0,0,0);
  G(EP_BIAS_RESB, Tb, Wf2T, Xb, 0, bf2, X2b, 0,0, 1.f, 32768,256,256, 256,256,256, 1,1, 0,0,0,0,0,0);
  G(EP_QP_GELU, Xb, Wh1T, H1b, 0, 0,0, qp, Wh1 + 65536, 1.f, 32768,256,256, 256,256,256, 1,1, 0,0,0,0,0,0);
  G(EP_GELU, H1b, Wh2T, H2b, 0, 0,0,0,0, 1.f, 32768,128,256, 256,256,128, 1,1, 0,0,0,0,0,0);
  k_final<<<dim3(128), dim3(256), 0, stream>>>(H2b, Wh3, bh3, out);
}

// Round 4
// 603.080 us; speedup vs baseline: 1.2485x; 1.0748x over previous
//
#include <hip/hip_runtime.h>
#include <math.h>

// PointWiseDecoder2DSimple on MI355X (gfx950)
// b=8, nq=nc=4096, LATENT=256, HEADS=4, DH=256, INNER=1024.
// R4: rot/inst-norm/transpose fused into the producing GEMM epilogues
// (gemm_fuse<MODE>), kv-GEMM operand-swapped for coalesced row-major
// partials. k_kvt / k_rot_q standalone kernels deleted.

typedef unsigned short u16;
typedef __attribute__((ext_vector_type(4))) float f32x4;
typedef __attribute__((ext_vector_type(8))) short s16x8;
typedef __attribute__((ext_vector_type(8))) unsigned short u16x8;
typedef __attribute__((ext_vector_type(4))) unsigned short u16x4;

#define LOG2_1E4_D64 0.20762050593046013f  // log2(10000)/64

__device__ __forceinline__ u16 f2b(float f){
  union { float f; unsigned u; } v; v.f = f;
  unsigned u = v.u;
  u += 0x7FFFu + ((u >> 16) & 1u);
  return (u16)(u >> 16);
}
__device__ __forceinline__ float b2f(u16 b){
  union { unsigned u; float f; } v; v.u = ((unsigned)b) << 16; return v.f;
}
__device__ __forceinline__ float gelu_f(float x){
  return 0.5f * x * (1.0f + erff(x * 0.7071067811865475f));
}

#if __has_builtin(__builtin_amdgcn_global_load_lds)
#define HAVE_GLL 1
typedef const __attribute__((address_space(1))) void* as1cv;
typedef __attribute__((address_space(3))) void* as3v;
__device__ __forceinline__ void gload16(const void* g, void* l){
  __builtin_amdgcn_global_load_lds((as1cv)g, (as3v)l, 16, 0, 0);
}
#else
#define HAVE_GLL 0
#endif

// ---------------- elementwise kernels ----------------

__global__ __launch_bounds__(256) void k_cast(const float* __restrict__ in, u16* __restrict__ out){
  long i = (long)blockIdx.x * 256 + threadIdx.x;
  float4 f = ((const float4*)in)[i];
  u16x4 o = { f2b(f.x), f2b(f.y), f2b(f.z), f2b(f.w) };
  ((u16x4*)out)[i] = o;
}

// all 9 weight transposes (f32 [K][N] -> bf16 [N][K]) in one launch
struct TCArgs {
  const float* W[9]; u16* Wt[9];
  int K[9]; int N[9]; int boff[10];
};
__global__ __launch_bounds__(256) void k_tcast_all(TCArgs a){
  int b = blockIdx.x;
  int w = 0;
  while (b >= a.boff[w+1]) w++;
  int idx = (b - a.boff[w]) * 256 + threadIdx.x;
  int K = a.K[w], N = a.N[w];
  int n = idx / K, k = idx - n * K;
  a.Wt[w][idx] = f2b(a.W[w][(long)k * N + n]);
}

__global__ __launch_bounds__(256) void k_fourier(const float* __restrict__ qp, const float* __restrict__ Bff, u16* __restrict__ X0){
  int tid = threadIdx.x;
  long r = (long)blockIdx.x * 2 + (tid >> 7);
  int j = tid & 127;
  float qx = qp[r*2], qy = qp[r*2+1];
  float ff = 6.283185307179586f * (qx * Bff[j] + qy * Bff[128 + j]);
  X0[r*256 + j]       = f2b(sinf(ff));
  X0[r*256 + 128 + j] = f2b(cosf(ff));
}

// split-K reduce: kvT[i] = bf16(sum_sp p[sp][i]), SPL=4
__global__ __launch_bounds__(256) void k_red(const float* __restrict__ p, u16* __restrict__ out, long stride){
  long i = (long)blockIdx.x * 256 + threadIdx.x;
  f32x4 s = ((const f32x4*)p)[i];
  s += ((const f32x4*)(p + stride))[i];
  s += ((const f32x4*)(p + 2*stride))[i];
  s += ((const f32x4*)(p + 3*stride))[i];
  u16x4 o = { f2b(s[0]), f2b(s[1]), f2b(s[2]), f2b(s[3]) };
  ((u16x4*)out)[i] = o;
}

// final head: out = H2 @ Wh3 + bh3  (N=3, K=128), fp32
__global__ __launch_bounds__(256) void k_final(const u16* __restrict__ H2, const float* __restrict__ Wh3,
                                               const float* __restrict__ bh3, float* __restrict__ out){
  long r = (long)blockIdx.x * 256 + threadIdx.x;
  float a0 = bh3[0], a1 = bh3[1], a2 = bh3[2];
  const u16x8* hrow = (const u16x8*)(H2 + r*128);
#pragma unroll
  for (int c8 = 0; c8 < 16; c8++){
    u16x8 hv = hrow[c8];
#pragma unroll
    for (int e = 0; e < 8; e++){
      float f = b2f(hv[e]);
      int k = c8*8 + e;
      a0 += f * Wh3[k*3];
      a1 += f * Wh3[k*3+1];
      a2 += f * Wh3[k*3+2];
    }
  }
  out[r*3] = a0; out[r*3+1] = a1; out[r*3+2] = a2;
}

// ---------------- fused projection GEMM: one head per block-column ----------------
// C128x256 = A[128,256] * B[256,256]^T  then per MODE:
//   0: rotary + inst_norm + transposed store to [mat][d][n]   (K path)
//   1: inst_norm + transposed store                           (V path)
//   2: rotary + direct store [n][h*256+d]                     (Q path)
// 4 waves: wm=(w&1)*64, wn=(w>>1)*128. With BN=256 the rot pair (d,d+64)
// is lane-local: acc[i][j] <-> acc[i][j+4].

template<int MODE>
__global__ __launch_bounds__(256, 2)
void gemm_fuse(const u16* __restrict__ A, const u16* __restrict__ Bw,
               u16* __restrict__ out, const float* __restrict__ pos){
  __shared__ u16 As[128*32];
  __shared__ u16 Bs[256*32];

  int tid  = threadIdx.x;
  int lane = tid & 63;
  int wave = tid >> 6;
  int wm = (wave & 1) << 6;
  int wn = (wave >> 1) << 7;
  int whalf = wave >> 1;          // 0: cols 0..127 (x-axis), 1: cols 128..255 (y-axis)
  int h = blockIdx.y;
  long m0 = (long)blockIdx.x * 128;

  int r15 = lane & 15;
  int cc  = lane >> 4;
  const u16* Bh = Bw + (long)h * 65536;

#if HAVE_GLL
  int srow = lane >> 2;
  int scol = (lane & 3) * 8;
  u16* lA[2]; const u16* gA[2];
#pragma unroll
  for (int t = 0; t < 2; t++){
    int rb = (wave*2 + t) * 16;
    lA[t] = &As[rb*32];
    gA[t] = A + (m0 + rb + srow) * 256 + scol;
  }
  u16* lB[4]; const u16* gB[4];
#pragma unroll
  for (int t = 0; t < 4; t++){
    int rb = (wave*4 + t) * 16;
    lB[t] = &Bs[rb*32];
    gB[t] = Bh + (rb + srow) * 256 + scol;
  }
#else
  int sm  = tid >> 2;
  int sc  = tid & 3;
#endif

  f32x4 acc[4][8];
#pragma unroll
  for (int i = 0; i < 4; i++)
#pragma unroll
    for (int j = 0; j < 8; j++)
      acc[i][j] = f32x4{0.f, 0.f, 0.f, 0.f};

  for (int k0 = 0; k0 < 256; k0 += 32){
#if HAVE_GLL
    __syncthreads();
#pragma unroll
    for (int t = 0; t < 2; t++) gload16(gA[t] + k0, lA[t]);
#pragma unroll
    for (int t = 0; t < 4; t++) gload16(gB[t] + k0, lB[t]);
    __syncthreads();
#else
    u16x8 va = *(const u16x8*)(A + (m0 + sm)*256 + sc*8 + k0);
    u16x8 vb0 = *(const u16x8*)(Bh + (sm      )*256 + sc*8 + k0);
    u16x8 vb1 = *(const u16x8*)(Bh + (sm + 64 )*256 + sc*8 + k0);
    u16x8 vb2 = *(const u16x8*)(Bh + (sm + 128)*256 + sc*8 + k0);
    u16x8 vb3 = *(const u16x8*)(Bh + (sm + 192)*256 + sc*8 + k0);
    u16x8 va1 = *(const u16x8*)(A + (m0 + sm + 64)*256 + sc*8 + k0);
    __syncthreads();
    *(u16x8*)&As[sm*32 + sc*8] = va;
    *(u16x8*)&As[(sm+64)*32 + sc*8] = va1;
    *(u16x8*)&Bs[sm*32 + sc*8] = vb0;
    *(u16x8*)&Bs[(sm+64)*32 + sc*8] = vb1;
    *(u16x8*)&Bs[(sm+128)*32 + sc*8] = vb2;
    *(u16x8*)&Bs[(sm+192)*32 + sc*8] = vb3;
    __syncthreads();
#endif
    s16x8 af[4], bf[8];
#pragma unroll
    for (int i = 0; i < 4; i++) af[i] = *(const s16x8*)&As[(wm + i*16 + r15)*32 + cc*8];
#pragma unroll
    for (int j = 0; j < 8; j++) bf[j] = *(const s16x8*)&Bs[(wn + j*16 + r15)*32 + cc*8];
#pragma unroll
    for (int i = 0; i < 4; i++)
#pragma unroll
      for (int j = 0; j < 8; j++)
        acc[i][j] = __builtin_amdgcn_mfma_f32_16x16x32_bf16(af[i], bf[j], acc[i][j], 0, 0, 0);
  }

  // ---- rotary (K and Q): pair acc[i][j] <-> acc[i][j+4]; axis = whalf
  if constexpr (MODE != 1){
    float invf4[4];
#pragma unroll
    for (int jl = 0; jl < 4; jl++)
      invf4[jl] = 1024.0f * exp2f(-(float)(jl*16 + r15) * LOG2_1E4_D64);
#pragma unroll
    for (int i = 0; i < 4; i++){
#pragma unroll
      for (int r = 0; r < 4; r++){
        long n = m0 + wm + i*16 + cc*4 + r;
        float p = pos[n*2 + whalf];
#pragma unroll
        for (int jl = 0; jl < 4; jl++){
          float a = p * invf4[jl];
          float s = __sinf(a), c = __cosf(a);
          float t0 = acc[i][jl][r], t1 = acc[i][jl+4][r];
          acc[i][jl][r]   = t0*c - t1*s;
          acc[i][jl+4][r] = t1*c + t0*s;
        }
      }
    }
  }

  if constexpr (MODE == 2){
    // direct store [n][h*256 + d]
#pragma unroll
    for (int i = 0; i < 4; i++)
#pragma unroll
      for (int j = 0; j < 8; j++)
#pragma unroll
        for (int r = 0; r < 4; r++){
          long row = m0 + wm + i*16 + cc*4 + r;
          int col = h*256 + wn + j*16 + r15;
          out[row*1024 + col] = f2b(acc[i][j][r]);
        }
  } else {
    // ---- inst_norm over the 256 head dims, then transposed store
    __shared__ float PS1[2][128];
    __shared__ float PS2[2][128];
    __shared__ u16 TB[64*256];

    float s1a[4][4], s2a[4][4];
#pragma unroll
    for (int i = 0; i < 4; i++){
#pragma unroll
      for (int r = 0; r < 4; r++){
        float s1 = 0.f, s2 = 0.f;
#pragma unroll
        for (int j = 0; j < 8; j++){
          float v = acc[i][j][r];
          s1 += v; s2 += v*v;
        }
#pragma unroll
        for (int m = 1; m < 16; m <<= 1){
          s1 += __shfl_xor(s1, m, 64);
          s2 += __shfl_xor(s2, m, 64);
        }
        s1a[i][r] = s1; s2a[i][r] = s2;
        int rowid = (wave&1)*64 + i*16 + cc*4 + r;
        if (r15 == 0){ PS1[whalf][rowid] = s1; PS2[whalf][rowid] = s2; }
      }
    }
    __syncthreads();
#pragma unroll
    for (int i = 0; i < 4; i++){
#pragma unroll
      for (int r = 0; r < 4; r++){
        int rowid = (wave&1)*64 + i*16 + cc*4 + r;
        float s1 = PS1[0][rowid] + PS1[1][rowid];
        float s2 = PS2[0][rowid] + PS2[1][rowid];
        float mu  = s1 * 0.00390625f;
        float var = s2 * 0.00390625f - mu*mu;
        float inv = 1.0f / sqrtf(var + 1e-5f);
#pragma unroll
        for (int j = 0; j < 8; j++)
          acc[i][j] = f32x4{ (acc[i][j][0+0]-0.f), acc[i][j][1], acc[i][j][2], acc[i][j][3] },
          acc[i][j][r] = (acc[i][j][r] - mu) * inv;
      }
    }
    __syncthreads();

    // transposed store via LDS bounce (two 64-row passes; proven k_kvt pattern)
    int bb  = (int)(m0 >> 12);          // chunk-local batch
    int nn0 = (int)(m0 & 4095);
    long matbase = ((long)(bb*4 + h) * 256) * 4096;
#pragma unroll
    for (int p = 0; p < 2; p++){
      if ((wave & 1) == p){
#pragma unroll
        for (int i = 0; i < 4; i++)
#pragma unroll
          for (int j = 0; j < 8; j++)
#pragma unroll
            for (int r = 0; r < 4; r++){
              int nl = i*16 + cc*4 + r;
              int d  = wn + j*16 + r15;
              TB[nl*256 + (d ^ ((nl>>2)<<1))] = f2b(acc[i][j][r]);
            }
      }
      __syncthreads();
      {
        int n4 = (lane & 15) * 4;
        int sw = (lane & 15) << 1;
#pragma unroll
        for (int rnd = 0; rnd < 16; rnd++){
          int d = rnd*16 + wave*4 + (lane >> 4);
          u16x4 vv;
#pragma unroll
          for (int jj = 0; jj < 4; jj++) vv[jj] = TB[(n4+jj)*256 + (d ^ sw)];
          *(u16x4*)(out + matbase + (long)d*4096 + nn0 + p*64 + n4) = vv;
        }
      }
      __syncthreads();
    }
  }
}

// ---------------- generic GEMM: C = A[M,K] * B[N,K]^T, 128x128 tile ----------------

enum { EP_B = 0, EP_GELU = 1, EP_BIAS_GELU = 2, EP_BIAS_RESB = 3, EP_SCALE = 4,
       EP_QP_GELU = 5, EP_F32 = 6 };

struct GArgs {
  const u16* A; const u16* B;
  u16* Cb; float* Cf;
  const float* bias; const u16* res; const float* qp; const float* wtail;
  float scale;
  int M, N, K, lda, ldb, ldc, NLO;
  long sAh, sAl, sBh, sBl, sCh, sCl;
};

template<int EP>
__global__ __launch_bounds__(256, 2)
void gemm_k(GArgs g){
  int z = blockIdx.z;
  int zh = z / g.NLO, zl = z - zh * g.NLO;
  const u16* A = g.A + (long)zh * g.sAh + (long)zl * g.sAl;
  const u16* B = g.B + (long)zh * g.sBh + (long)zl * g.sBl;
  long coff = (long)zh * g.sCh + (long)zl * g.sCl;

  __shared__ u16 As[128*32];
  __shared__ u16 Bs[128*32];

  int tid  = threadIdx.x;
  int lane = tid & 63;
  int wave = tid >> 6;
  int wm = (wave & 1) << 6;
  int wn = (wave >> 1) << 6;
  long m0 = (long)blockIdx.x * 128;
  long n0 = (long)blockIdx.y * 128;

  int r15 = lane & 15;
  int cc  = lane >> 4;

#if HAVE_GLL
  int rA0 = (wave*2 + 0) * 16;
  int rA1 = (wave*2 + 1) * 16;
  int srow = lane >> 2;
  int scol = (lane & 3) * 8;
  u16* lA0 = &As[rA0*32];
  u16* lA1 = &As[rA1*32];
  u16* lB0 = &Bs[rA0*32];
  u16* lB1 = &Bs[rA1*32];
  const u16* gA0 = A + (m0 + rA0 + srow) * g.lda + scol;
  const u16* gA1 = A + (m0 + rA1 + srow) * g.lda + scol;
  const u16* gB0 = B + (n0 + rA0 + srow) * g.ldb + scol;
  const u16* gB1 = B + (n0 + rA1 + srow) * g.ldb + scol;
#else
  int sm  = tid >> 2;
  int sc  = tid & 3;
  int so0 = sm * 32 + sc * 8;
  int so1 = (sm + 64) * 32 + sc * 8;
  const u16* pA0 = A + (m0 + sm ) * g.lda + sc * 8;
  const u16* pA1 = A + (m0 + sm + 64) * g.lda + sc * 8;
  const u16* pB0 = B + (n0 + sm ) * g.ldb + sc * 8;
  const u16* pB1 = B + (n0 + sm + 64) * g.ldb + sc * 8;
#endif

  f32x4 acc[4][4];
#pragma unroll
  for (int i = 0; i < 4; i++)
#pragma unroll
    for (int j = 0; j < 4; j++)
      acc[i][j] = f32x4{0.f, 0.f, 0.f, 0.f};

  for (int k0 = 0; k0 < g.K; k0 += 32){
#if HAVE_GLL
    __syncthreads();
    gload16(gA0 + k0, lA0);
    gload16(gA1 + k0, lA1);
    gload16(gB0 + k0, lB0);
    gload16(gB1 + k0, lB1);
    __syncthreads();
#else
    u16x8 va0 = *(const u16x8*)(pA0 + k0);
    u16x8 va1 = *(const u16x8*)(pA1 + k0);
    u16x8 vb0 = *(const u16x8*)(pB0 + k0);
    u16x8 vb1 = *(const u16x8*)(pB1 + k0);
    __syncthreads();
    *(u16x8*)&As[so0] = va0;
    *(u16x8*)&As[so1] = va1;
    *(u16x8*)&Bs[so0] = vb0;
    *(u16x8*)&Bs[so1] = vb1;
    __syncthreads();
#endif
    s16x8 af[4], bf[4];
#pragma unroll
    for (int i = 0; i < 4; i++) af[i] = *(const s16x8*)&As[(wm + i*16 + r15)*32 + cc*8];
#pragma unroll
    for (int i = 0; i < 4; i++) bf[i] = *(const s16x8*)&Bs[(wn + i*16 + r15)*32 + cc*8];
#pragma unroll
    for (int i = 0; i < 4; i++)
#pragma unroll
      for (int j = 0; j < 4; j++)
        acc[i][j] = __builtin_amdgcn_mfma_f32_16x16x32_bf16(af[i], bf[j], acc[i][j], 0, 0, 0);
  }

  int colb = (int)n0 + wn + r15;
  int rowb = (int)m0 + wm + cc * 4;
#pragma unroll
  for (int i = 0; i < 4; i++){
#pragma unroll
    for (int j = 0; j < 4; j++){
      int col = colb + j*16;
#pragma unroll
      for (int r = 0; r < 4; r++){
        int row = rowb + i*16 + r;
        float v = acc[i][j][r];
        if constexpr (EP == EP_B){
          g.Cb[coff + (long)row * g.ldc + col] = f2b(v);
        } else if constexpr (EP == EP_GELU){
          g.Cb[coff + (long)row * g.ldc + col] = f2b(gelu_f(v));
        } else if constexpr (EP == EP_BIAS_GELU){
          v = gelu_f(v + g.bias[col]);
          g.Cb[coff + (long)row * g.ldc + col] = f2b(v);
        } else if constexpr (EP == EP_BIAS_RESB){
          v += g.bias[col] + b2f(g.res[(long)row * g.ldc + col]);
          g.Cb[coff + (long)row * g.ldc + col] = f2b(v);
        } else if constexpr (EP == EP_SCALE){
          g.Cb[coff + (long)row * g.ldc + col] = f2b(v * g.scale);
        } else if constexpr (EP == EP_F32){
          g.Cf[coff + (long)row * g.ldc + col] = v;
        } else { // EP_QP_GELU: rank-2 update for [x, query_pos] concat (Wh1 rows 256,257)
          v += g.qp[(long)row*2] * g.wtail[col] + g.qp[(long)row*2+1] * g.wtail[256+col];
          g.Cb[coff + (long)row * g.ldc + col] = f2b(gelu_f(v));
        }
      }
    }
  }
}

// ---------------- host ----------------

extern "C" void kernel_launch(void* const* d_in, const int* in_sizes, int n_in,
                              void* d_out, int out_size, void* d_ws, size_t ws_size,
                              hipStream_t stream){
  const float* z   = (const float*)d_in[0];
  const float* qp  = (const float*)d_in[1];
  const float* cp  = (const float*)d_in[2];
  const float* Bff = (const float*)d_in[3];
  const float* Wc1 = (const float*)d_in[4];
  const float* Wc2 = (const float*)d_in[5];
  const float* Wq  = (const float*)d_in[6];
  const float* Wkv = (const float*)d_in[7];
  const float* Wo  = (const float*)d_in[8];
  const float* bo  = (const float*)d_in[9];
  const float* Wf1 = (const float*)d_in[10];
  const float* bf1 = (const float*)d_in[11];
  const float* Wf2 = (const float*)d_in[12];
  const float* bf2 = (const float*)d_in[13];
  const float* Wh1 = (const float*)d_in[14];
  const float* Wh2 = (const float*)d_in[15];
  const float* Wh3 = (const float*)d_in[16];
  const float* bh3 = (const float*)d_in[17];
  float* out = (float*)d_out;
  (void)in_sizes; (void)n_in; (void)out_size;

  size_t mb = ws_size >> 20;
  int C;
  if      (mb >= 264) C = 1;
  else if (mb >= 168) C = 2;
  else if (mb >= 120) C = 4;
  else                C = 8;
  const int NB = 8 / C;
  const long R = (long)NB * 4096;

  char* ws = (char*)d_ws;
  const size_t MB = 1024*1024;
  u16* WqT  = (u16*)(ws + 0);
  u16* WkvT = (u16*)(ws + 512*1024);
  u16* WoT  = (u16*)(ws + 1536*1024);
  u16* Wc1T = (u16*)(ws + 2048*1024);
  u16* Wc2T = (u16*)(ws + (2048+128)*1024);
  u16* Wf1T = (u16*)(ws + (2048+256)*1024);
  u16* Wf2T = (u16*)(ws + (2048+384)*1024);
  u16* Wh1T = (u16*)(ws + (2048+512)*1024);
  u16* Wh2T = (u16*)(ws + (2048+640)*1024);
  u16* R1 = (u16*)(ws + 4*MB);    // X0b -> X2b
  u16* R2 = (u16*)(ws + 20*MB);   // Tb -> H1b
  u16* R3 = (u16*)(ws + 36*MB);   // Xb -> X3
  u16* R4 = (u16*)(ws + 52*MB);   // Zb -> H2b
  u16* kvT = (u16*)(ws + 68*MB);  // 4MB: 32 mats [e=256][d=256]
  u16* BIG1 = (u16*)(ws + 72*MB);                     // kv f32 partials -> Qb
  u16* BIG2 = (u16*)((char*)BIG1 + (size_t)NB*8*MB);  // Kt -> ATTb
  u16* BIG3 = (u16*)((char*)BIG2 + (size_t)NB*8*MB);  // Vt

  u16* X0b = R1; u16* X2b = R1;
  u16* Tb  = R2; u16* H1b = R2;
  u16* Xb  = R3;
  u16* Zb  = R4; u16* H2b = R4;

  auto G = [&](int ep, const u16* A, const u16* B, u16* Cb, float* Cf,
               const float* bias, const u16* res, const float* qq, const float* wtail,
               float scale, int M, int N, int K, int lda, int ldb, int ldc,
               int nz, int NLO, long sAh, long sAl, long sBh, long sBl, long sCh, long sCl){
    GArgs g;
    g.A=A; g.B=B; g.Cb=Cb; g.Cf=Cf; g.bias=bias; g.res=res; g.qp=qq; g.wtail=wtail;
    g.scale=scale; g.M=M; g.N=N; g.K=K; g.lda=lda; g.ldb=ldb; g.ldc=ldc; g.NLO=NLO;
    g.sAh=sAh; g.sAl=sAl; g.sBh=sBh; g.sBl=sBl; g.sCh=sCh; g.sCl=sCl;
    dim3 gr(M/128, N/128, nz); dim3 bl(256);
    switch(ep){
      case EP_B:          gemm_k<EP_B><<<gr,bl,0,stream>>>(g); break;
      case EP_GELU:       gemm_k<EP_GELU><<<gr,bl,0,stream>>>(g); break;
      case EP_BIAS_GELU:  gemm_k<EP_BIAS_GELU><<<gr,bl,0,stream>>>(g); break;
      case EP_BIAS_RESB:  gemm_k<EP_BIAS_RESB><<<gr,bl,0,stream>>>(g); break;
      case EP_SCALE:      gemm_k<EP_SCALE><<<gr,bl,0,stream>>>(g); break;
      case EP_QP_GELU:    gemm_k<EP_QP_GELU><<<gr,bl,0,stream>>>(g); break;
      case EP_F32:        gemm_k<EP_F32><<<gr,bl,0,stream>>>(g); break;
    }
  };

  // ---- weight prep + z cast
  k_cast<<<dim3(8192), dim3(256), 0, stream>>>(z, Zb);
  {
    TCArgs a;
    const float* Ws[9] = { Wq, Wkv, Wo, Wc1, Wc2, Wf1, Wf2, Wh1, Wh2 };
    u16* Wts[9] = { WqT, WkvT, WoT, Wc1T, Wc2T, Wf1T, Wf2T, Wh1T, Wh2T };
    int Ks[9] = { 256, 256, 1024, 256, 256, 256, 256, 256, 256 };
    int Ns[9] = { 1024, 2048, 256, 256, 256, 256, 256, 256, 128 };
    int off = 0;
    for (int i = 0; i < 9; i++){
      a.W[i] = Ws[i]; a.Wt[i] = Wts[i]; a.K[i] = Ks[i]; a.N[i] = Ns[i];
      a.boff[i] = off; off += Ks[i]*Ns[i]/256;
    }
    a.boff[9] = off;
    k_tcast_all<<<dim3(off), dim3(256), 0, stream>>>(a);
  }

  // ---- query trunk
  k_fourier<<<dim3(16384), dim3(256), 0, stream>>>(qp, Bff, X0b);
  G(EP_GELU, X0b, Wc1T, Tb, 0, 0,0,0,0, 1.f, 32768,256,256, 256,256,256, 1,1, 0,0,0,0,0,0);
  G(EP_B,    Tb,  Wc2T, Xb, 0, 0,0,0,0, 1.f, 32768,256,256, 256,256,256, 1,1, 0,0,0,0,0,0);

  // ---- attention arm, per batch-chunk
  for (int c = 0; c < C; c++){
    long row0 = (long)c * R;
    const u16* Zc = Zb + row0 * 256;
    // K = rot(norm^-( z@Wkv[:, :1024] )) -> Kt [mat][d][n]
    gemm_fuse<0><<<dim3((int)(R/128), 4), dim3(256), 0, stream>>>(Zc, WkvT, BIG2, cp + row0*2);
    // V = norm( z@Wkv[:, 1024:] ) -> Vt
    gemm_fuse<1><<<dim3((int)(R/128), 4), dim3(256), 0, stream>>>(Zc, WkvT + 1024*256, BIG3, cp + row0*2);
    // kv^T[e][d] = sum_n V[n,e] K[n,d], split-K 4 -> f32 partials, then reduce to bf16
    G(EP_F32, BIG3, BIG2, 0, (float*)BIG1, 0,0,0,0, 1.f,
      256,256,1024, 4096,4096,256, 4*NB*4, NB*4,
      1024,1048576, 1024,1048576, (long)NB*4*65536,65536);
    k_red<<<dim3(NB*256), dim3(256), 0, stream>>>((float*)BIG1, kvT + (long)c*NB*4*65536, (long)NB*4*65536);
    // Q = rot(x@Wq) -> [n][h*256+d]
    gemm_fuse<2><<<dim3((int)(R/128), 4), dim3(256), 0, stream>>>(Xb + row0*256, WqT, BIG1, qp + row0*2);
    // attn = q@kv * (1/nc)
    G(EP_SCALE, BIG1, kvT + (long)c*NB*4*65536, BIG2, 0, 0,0,0,0, 1.0f/4096.0f,
      4096,256,256, 1024,256,1024, NB*4,4, 4194304,256, 262144,65536, 4194304,256);
    // x2 = attn@Wo + bo + x
    G(EP_BIAS_RESB, BIG2, WoT, X2b + row0*256, 0, bo, Xb + row0*256, 0,0, 1.f,
      (int)R,256,1024, 1024,1024,256, 1,1, 0,0,0,0,0,0);
  }

  // ---- FF block + head MLP
  G(EP_BIAS_GELU, X2b, Wf1T, Tb, 0, bf1, 0,0,0, 1.f, 32768,256,256, 256,256,256, 1,1, 0,0,0,0,0,0);
  G(EP_BIAS_RESB, Tb, Wf2T, Xb, 0, bf2, X2b, 0,0, 1.f, 32768,256,256, 256,256,256, 1,1, 0,0,0,0,0,0);
  G(EP_QP_GELU, Xb, Wh1T, H1b, 0, 0,0, qp, Wh1 + 65536, 1.f, 32768,256,256, 256,256,256, 1,1, 0,0,0,0,0,0);
  G(EP_GELU, H1b, Wh2T, H2b, 0, 0,0,0,0, 1.f, 32768,128,256, 256,256,128, 1,1, 0,0,0,0,0,0);
  k_final<<<dim3(128), dim3(256), 0, stream>>>(H2b, Wh3, bh3, out);
}

// Round 5
// 540.437 us; speedup vs baseline: 1.3933x; 1.1159x over previous
//
#include <hip/hip_runtime.h>
#include <math.h>

// PointWiseDecoder2DSimple on MI355X (gfx950)
// b=8, nq=nc=4096, LATENT=256, HEADS=4, DH=256, INNER=1024.
// R5: double-buffered 2-phase staging (issue-next -> compute-cur -> barrier)
// in all MFMA kernels (T3 minimum recipe); K-fuse + V-fuse merged into one
// dispatch; fuse epilogue LDS aliased into staging buffers (48KB total).

typedef unsigned short u16;
typedef __attribute__((ext_vector_type(4))) float f32x4;
typedef __attribute__((ext_vector_type(8))) short s16x8;
typedef __attribute__((ext_vector_type(8))) unsigned short u16x8;
typedef __attribute__((ext_vector_type(4))) unsigned short u16x4;

#define LOG2_1E4_D64 0.20762050593046013f  // log2(10000)/64

__device__ __forceinline__ u16 f2b(float f){
  union { float f; unsigned u; } v; v.f = f;
  unsigned u = v.u;
  u += 0x7FFFu + ((u >> 16) & 1u);
  return (u16)(u >> 16);
}
__device__ __forceinline__ float b2f(u16 b){
  union { unsigned u; float f; } v; v.u = ((unsigned)b) << 16; return v.f;
}
__device__ __forceinline__ float gelu_f(float x){
  return 0.5f * x * (1.0f + erff(x * 0.7071067811865475f));
}

#if __has_builtin(__builtin_amdgcn_global_load_lds)
#define HAVE_GLL 1
typedef const __attribute__((address_space(1))) void* as1cv;
typedef __attribute__((address_space(3))) void* as3v;
__device__ __forceinline__ void gload16(const void* g, void* l){
  __builtin_amdgcn_global_load_lds((as1cv)g, (as3v)l, 16, 0, 0);
}
#else
#define HAVE_GLL 0
#endif

// ---------------- elementwise kernels ----------------

__global__ __launch_bounds__(256) void k_cast(const float* __restrict__ in, u16* __restrict__ out){
  long i = (long)blockIdx.x * 256 + threadIdx.x;
  float4 f = ((const float4*)in)[i];
  u16x4 o = { f2b(f.x), f2b(f.y), f2b(f.z), f2b(f.w) };
  ((u16x4*)out)[i] = o;
}

// all 9 weight transposes (f32 [K][N] -> bf16 [N][K]) in one launch
struct TCArgs {
  const float* W[9]; u16* Wt[9];
  int K[9]; int N[9]; int boff[10];
};
__global__ __launch_bounds__(256) void k_tcast_all(TCArgs a){
  int b = blockIdx.x;
  int w = 0;
  while (b >= a.boff[w+1]) w++;
  int idx = (b - a.boff[w]) * 256 + threadIdx.x;
  int K = a.K[w], N = a.N[w];
  int n = idx / K, k = idx - n * K;
  a.Wt[w][idx] = f2b(a.W[w][(long)k * N + n]);
}

__global__ __launch_bounds__(256) void k_fourier(const float* __restrict__ qp, const float* __restrict__ Bff, u16* __restrict__ X0){
  int tid = threadIdx.x;
  long r = (long)blockIdx.x * 2 + (tid >> 7);
  int j = tid & 127;
  float qx = qp[r*2], qy = qp[r*2+1];
  float ff = 6.283185307179586f * (qx * Bff[j] + qy * Bff[128 + j]);
  X0[r*256 + j]       = f2b(sinf(ff));
  X0[r*256 + 128 + j] = f2b(cosf(ff));
}

// split-K reduce: kvT[i] = bf16(sum_sp p[sp][i]), SPL=4
__global__ __launch_bounds__(256) void k_red(const float* __restrict__ p, u16* __restrict__ out, long stride){
  long i = (long)blockIdx.x * 256 + threadIdx.x;
  f32x4 s = ((const f32x4*)p)[i];
  s += ((const f32x4*)(p + stride))[i];
  s += ((const f32x4*)(p + 2*stride))[i];
  s += ((const f32x4*)(p + 3*stride))[i];
  u16x4 o = { f2b(s[0]), f2b(s[1]), f2b(s[2]), f2b(s[3]) };
  ((u16x4*)out)[i] = o;
}

// final head: out = H2 @ Wh3 + bh3  (N=3, K=128), fp32
__global__ __launch_bounds__(256) void k_final(const u16* __restrict__ H2, const float* __restrict__ Wh3,
                                               const float* __restrict__ bh3, float* __restrict__ out){
  long r = (long)blockIdx.x * 256 + threadIdx.x;
  float a0 = bh3[0], a1 = bh3[1], a2 = bh3[2];
  const u16x8* hrow = (const u16x8*)(H2 + r*128);
#pragma unroll
  for (int c8 = 0; c8 < 16; c8++){
    u16x8 hv = hrow[c8];
#pragma unroll
    for (int e = 0; e < 8; e++){
      float f = b2f(hv[e]);
      int k = c8*8 + e;
      a0 += f * Wh3[k*3];
      a1 += f * Wh3[k*3+1];
      a2 += f * Wh3[k*3+2];
    }
  }
  out[r*3] = a0; out[r*3+1] = a1; out[r*3+2] = a2;
}

// ---------------- fused projection GEMM: one head per block-x ----------------
// C[128x256] = A[128,256] * Bh[256,256]^T  then per MODE:
//   0: KV combined — x<4: K-head (rotary+norm+T-store), x>=4: V-head (norm+T-store)
//   1: Q — rotary + direct store [n][x*256+d]
// 4 waves: wm=(w&1)*64, wn=(w>>1)*128. Rot pair (d,d+64) lane-local (j <-> j+4).
// Double-buffered staging; epilogue TB/PS alias the staging LDS (48KB total).

template<int MODE>
__global__ __launch_bounds__(256, 2)
void gemm_fuse(const u16* __restrict__ A, const u16* __restrict__ Bw,
               u16* __restrict__ outK, u16* __restrict__ outV,
               const float* __restrict__ pos){
  __shared__ char smem[49152];
  u16* AsB[2] = { (u16*)smem,            (u16*)(smem + 8192)  };
  u16* BsB[2] = { (u16*)(smem + 16384),  (u16*)(smem + 32768) };

  int tid  = threadIdx.x;
  int lane = tid & 63;
  int wave = tid >> 6;
  int wm = (wave & 1) << 6;
  int wn = (wave >> 1) << 7;
  int whalf = wave >> 1;          // 0: cols 0..127 (x-axis), 1: cols 128..255 (y-axis)
  int yb = blockIdx.x;
  int h  = yb & 3;
  bool isK = (MODE == 1) || (yb < 4);
  long m0 = (long)blockIdx.y * 128;

  int r15 = lane & 15;
  int cc  = lane >> 4;
  const u16* Bh = Bw + (long)yb * 65536;

  int srow = lane >> 2;
  int scol = (lane & 3) * 8;
  int aRow[2], bRow[4];
  const u16 *gA[2], *gB[4];
#pragma unroll
  for (int t = 0; t < 2; t++){
    aRow[t] = (wave*2 + t) * 16;
    gA[t] = A + (m0 + aRow[t] + srow) * 256 + scol;
  }
#pragma unroll
  for (int t = 0; t < 4; t++){
    bRow[t] = (wave*4 + t) * 16;
    gB[t] = Bh + (bRow[t] + srow) * 256 + scol;
  }

  f32x4 acc[4][8];
#pragma unroll
  for (int i = 0; i < 4; i++)
#pragma unroll
    for (int j = 0; j < 8; j++)
      acc[i][j] = f32x4{0.f, 0.f, 0.f, 0.f};

#if HAVE_GLL
  // prologue: stage tile 0 into buf 0
#pragma unroll
  for (int t = 0; t < 2; t++) gload16(gA[t], AsB[0] + aRow[t]*32);
#pragma unroll
  for (int t = 0; t < 4; t++) gload16(gB[t], BsB[0] + bRow[t]*32);
  __syncthreads();
  int cur = 0;
  for (int k0 = 0; k0 < 256; k0 += 32){
    int nxt = cur ^ 1;
    if (k0 < 224){
#pragma unroll
      for (int t = 0; t < 2; t++) gload16(gA[t] + k0 + 32, AsB[nxt] + aRow[t]*32);
#pragma unroll
      for (int t = 0; t < 4; t++) gload16(gB[t] + k0 + 32, BsB[nxt] + bRow[t]*32);
    }
    s16x8 af[4], bf[8];
#pragma unroll
    for (int i = 0; i < 4; i++) af[i] = *(const s16x8*)&AsB[cur][(wm + i*16 + r15)*32 + cc*8];
#pragma unroll
    for (int j = 0; j < 8; j++) bf[j] = *(const s16x8*)&BsB[cur][(wn + j*16 + r15)*32 + cc*8];
#pragma unroll
    for (int i = 0; i < 4; i++)
#pragma unroll
      for (int j = 0; j < 8; j++)
        acc[i][j] = __builtin_amdgcn_mfma_f32_16x16x32_bf16(af[i], bf[j], acc[i][j], 0, 0, 0);
    __syncthreads();
    cur = nxt;
  }
#else
  int sm = tid >> 2, sc = tid & 3;
  for (int k0 = 0; k0 < 256; k0 += 32){
    u16x8 va  = *(const u16x8*)(A + (m0 + sm)*256 + sc*8 + k0);
    u16x8 va1 = *(const u16x8*)(A + (m0 + sm + 64)*256 + sc*8 + k0);
    u16x8 vb0 = *(const u16x8*)(Bh + (sm      )*256 + sc*8 + k0);
    u16x8 vb1 = *(const u16x8*)(Bh + (sm + 64 )*256 + sc*8 + k0);
    u16x8 vb2 = *(const u16x8*)(Bh + (sm + 128)*256 + sc*8 + k0);
    u16x8 vb3 = *(const u16x8*)(Bh + (sm + 192)*256 + sc*8 + k0);
    __syncthreads();
    *(u16x8*)&AsB[0][sm*32 + sc*8] = va;
    *(u16x8*)&AsB[0][(sm+64)*32 + sc*8] = va1;
    *(u16x8*)&BsB[0][sm*32 + sc*8] = vb0;
    *(u16x8*)&BsB[0][(sm+64)*32 + sc*8] = vb1;
    *(u16x8*)&BsB[1][sm*32 + sc*8] = vb2;
    *(u16x8*)&BsB[1][(sm+64)*32 + sc*8] = vb3;
    __syncthreads();
    s16x8 af[4], bf[8];
#pragma unroll
    for (int i = 0; i < 4; i++) af[i] = *(const s16x8*)&AsB[0][(wm + i*16 + r15)*32 + cc*8];
#pragma unroll
    for (int j = 0; j < 8; j++){
      int rr = wn + j*16 + r15;
      bf[j] = (rr < 128) ? *(const s16x8*)&BsB[0][rr*32 + cc*8]
                         : *(const s16x8*)&BsB[1][(rr-128)*32 + cc*8];
    }
#pragma unroll
    for (int i = 0; i < 4; i++)
#pragma unroll
      for (int j = 0; j < 8; j++)
        acc[i][j] = __builtin_amdgcn_mfma_f32_16x16x32_bf16(af[i], bf[j], acc[i][j], 0, 0, 0);
    __syncthreads();
  }
#endif

  // ---- rotary: pair acc[i][j] <-> acc[i][j+4]; axis = whalf
  if (isK){
    float invf4[4];
#pragma unroll
    for (int jl = 0; jl < 4; jl++)
      invf4[jl] = 1024.0f * exp2f(-(float)(jl*16 + r15) * LOG2_1E4_D64);
#pragma unroll
    for (int i = 0; i < 4; i++){
#pragma unroll
      for (int r = 0; r < 4; r++){
        long n = m0 + wm + i*16 + cc*4 + r;
        float p = pos[n*2 + whalf];
#pragma unroll
        for (int jl = 0; jl < 4; jl++){
          float a = p * invf4[jl];
          float s = __sinf(a), c = __cosf(a);
          float t0 = acc[i][jl][r], t1 = acc[i][jl+4][r];
          acc[i][jl][r]   = t0*c - t1*s;
          acc[i][jl+4][r] = t1*c + t0*s;
        }
      }
    }
  }

  if constexpr (MODE == 1){
    // Q: direct store [n][yb*256 + d]
#pragma unroll
    for (int i = 0; i < 4; i++)
#pragma unroll
      for (int j = 0; j < 8; j++)
#pragma unroll
        for (int r = 0; r < 4; r++){
          long row = m0 + wm + i*16 + cc*4 + r;
          int col = yb*256 + wn + j*16 + r15;
          outK[row*1024 + col] = f2b(acc[i][j][r]);
        }
  } else {
    // ---- inst_norm over 256 head dims, then transposed store [mat][d][n]
    u16*   TB  = (u16*)smem;               // 32KB, aliases AsB[0..1]+BsB[0]
    float* PS1 = (float*)(smem + 32768);   // [2][128], aliases BsB[1]
    float* PS2 = (float*)(smem + 33792);

#pragma unroll
    for (int i = 0; i < 4; i++){
#pragma unroll
      for (int r = 0; r < 4; r++){
        float s1 = 0.f, s2 = 0.f;
#pragma unroll
        for (int j = 0; j < 8; j++){
          float v = acc[i][j][r];
          s1 += v; s2 += v*v;
        }
#pragma unroll
        for (int m = 1; m < 16; m <<= 1){
          s1 += __shfl_xor(s1, m, 64);
          s2 += __shfl_xor(s2, m, 64);
        }
        int rowid = (wave&1)*64 + i*16 + cc*4 + r;
        if (r15 == 0){ PS1[whalf*128 + rowid] = s1; PS2[whalf*128 + rowid] = s2; }
      }
    }
    __syncthreads();
#pragma unroll
    for (int i = 0; i < 4; i++){
#pragma unroll
      for (int r = 0; r < 4; r++){
        int rowid = (wave&1)*64 + i*16 + cc*4 + r;
        float s1 = PS1[rowid] + PS1[128 + rowid];
        float s2 = PS2[rowid] + PS2[128 + rowid];
        float mu  = s1 * 0.00390625f;
        float var = s2 * 0.00390625f - mu*mu;
        float inv = 1.0f / sqrtf(var + 1e-5f);
#pragma unroll
        for (int j = 0; j < 8; j++)
          acc[i][j][r] = (acc[i][j][r] - mu) * inv;
      }
    }
    __syncthreads();

    u16* outp = isK ? outK : outV;
    int bb  = (int)(m0 >> 12);          // chunk-local batch
    int nn0 = (int)(m0 & 4095);
    long matbase = ((long)(bb*4 + h) * 256) * 4096;
#pragma unroll
    for (int p = 0; p < 2; p++){
      if ((wave & 1) == p){
#pragma unroll
        for (int i = 0; i < 4; i++)
#pragma unroll
          for (int j = 0; j < 8; j++)
#pragma unroll
            for (int r = 0; r < 4; r++){
              int nl = i*16 + cc*4 + r;
              int d  = wn + j*16 + r15;
              TB[nl*256 + (d ^ ((nl>>2)<<1))] = f2b(acc[i][j][r]);
            }
      }
      __syncthreads();
      {
        int n4 = (lane & 15) * 4;
        int sw = (lane & 15) << 1;
#pragma unroll
        for (int rnd = 0; rnd < 16; rnd++){
          int d = rnd*16 + wave*4 + (lane >> 4);
          u16x4 vv;
#pragma unroll
          for (int jj = 0; jj < 4; jj++) vv[jj] = TB[(n4+jj)*256 + (d ^ sw)];
          *(u16x4*)(outp + matbase + (long)d*4096 + nn0 + p*64 + n4) = vv;
        }
      }
      __syncthreads();
    }
  }
}

// ---------------- generic GEMM: C = A[M,K] * B[N,K]^T, 128x128 tile ----------------

enum { EP_B = 0, EP_GELU = 1, EP_BIAS_GELU = 2, EP_BIAS_RESB = 3, EP_SCALE = 4,
       EP_QP_GELU = 5, EP_F32 = 6 };

struct GArgs {
  const u16* A; const u16* B;
  u16* Cb; float* Cf;
  const float* bias; const u16* res; const float* qp; const float* wtail;
  float scale;
  int M, N, K, lda, ldb, ldc, NLO;
  long sAh, sAl, sBh, sBl, sCh, sCl;
};

template<int EP>
__global__ __launch_bounds__(256, 2)
void gemm_k(GArgs g){
  int z = blockIdx.z;
  int zh = z / g.NLO, zl = z - zh * g.NLO;
  const u16* A = g.A + (long)zh * g.sAh + (long)zl * g.sAl;
  const u16* B = g.B + (long)zh * g.sBh + (long)zl * g.sBl;
  long coff = (long)zh * g.sCh + (long)zl * g.sCl;

  __shared__ u16 As[2][128*32];
  __shared__ u16 Bs[2][128*32];

  int tid  = threadIdx.x;
  int lane = tid & 63;
  int wave = tid >> 6;
  int wm = (wave & 1) << 6;
  int wn = (wave >> 1) << 6;
  long m0 = (long)blockIdx.x * 128;
  long n0 = (long)blockIdx.y * 128;

  int r15 = lane & 15;
  int cc  = lane >> 4;

  f32x4 acc[4][4];
#pragma unroll
  for (int i = 0; i < 4; i++)
#pragma unroll
    for (int j = 0; j < 4; j++)
      acc[i][j] = f32x4{0.f, 0.f, 0.f, 0.f};

#if HAVE_GLL
  int srow = lane >> 2;
  int scol = (lane & 3) * 8;
  int aRow[2];
  const u16 *gA[2], *gB[2];
#pragma unroll
  for (int t = 0; t < 2; t++){
    aRow[t] = (wave*2 + t) * 16;
    gA[t] = A + (m0 + aRow[t] + srow) * g.lda + scol;
    gB[t] = B + (n0 + aRow[t] + srow) * g.ldb + scol;
  }
  // prologue: stage tile 0 into buf 0
#pragma unroll
  for (int t = 0; t < 2; t++){ gload16(gA[t], As[0] + aRow[t]*32); gload16(gB[t], Bs[0] + aRow[t]*32); }
  __syncthreads();
  int cur = 0;
  for (int k0 = 0; k0 < g.K; k0 += 32){
    int nxt = cur ^ 1;
    if (k0 + 32 < g.K){
#pragma unroll
      for (int t = 0; t < 2; t++){
        gload16(gA[t] + k0 + 32, As[nxt] + aRow[t]*32);
        gload16(gB[t] + k0 + 32, Bs[nxt] + aRow[t]*32);
      }
    }
    s16x8 af[4], bf[4];
#pragma unroll
    for (int i = 0; i < 4; i++) af[i] = *(const s16x8*)&As[cur][(wm + i*16 + r15)*32 + cc*8];
#pragma unroll
    for (int i = 0; i < 4; i++) bf[i] = *(const s16x8*)&Bs[cur][(wn + i*16 + r15)*32 + cc*8];
#pragma unroll
    for (int i = 0; i < 4; i++)
#pragma unroll
      for (int j = 0; j < 4; j++)
        acc[i][j] = __builtin_amdgcn_mfma_f32_16x16x32_bf16(af[i], bf[j], acc[i][j], 0, 0, 0);
    __syncthreads();
    cur = nxt;
  }
#else
  int sm  = tid >> 2;
  int sc  = tid & 3;
  for (int k0 = 0; k0 < g.K; k0 += 32){
    u16x8 va0 = *(const u16x8*)(A + (m0 + sm )*g.lda + sc*8 + k0);
    u16x8 va1 = *(const u16x8*)(A + (m0 + sm + 64)*g.lda + sc*8 + k0);
    u16x8 vb0 = *(const u16x8*)(B + (n0 + sm )*g.ldb + sc*8 + k0);
    u16x8 vb1 = *(const u16x8*)(B + (n0 + sm + 64)*g.ldb + sc*8 + k0);
    __syncthreads();
    *(u16x8*)&As[0][sm*32 + sc*8] = va0;
    *(u16x8*)&As[0][(sm+64)*32 + sc*8] = va1;
    *(u16x8*)&Bs[0][sm*32 + sc*8] = vb0;
    *(u16x8*)&Bs[0][(sm+64)*32 + sc*8] = vb1;
    __syncthreads();
    s16x8 af[4], bf[4];
#pragma unroll
    for (int i = 0; i < 4; i++) af[i] = *(const s16x8*)&As[0][(wm + i*16 + r15)*32 + cc*8];
#pragma unroll
    for (int i = 0; i < 4; i++) bf[i] = *(const s16x8*)&Bs[0][(wn + i*16 + r15)*32 + cc*8];
#pragma unroll
    for (int i = 0; i < 4; i++)
#pragma unroll
      for (int j = 0; j < 4; j++)
        acc[i][j] = __builtin_amdgcn_mfma_f32_16x16x32_bf16(af[i], bf[j], acc[i][j], 0, 0, 0);
    __syncthreads();
  }
#endif

  int colb = (int)n0 + wn + r15;
  int rowb = (int)m0 + wm + cc * 4;
#pragma unroll
  for (int i = 0; i < 4; i++){
#pragma unroll
    for (int j = 0; j < 4; j++){
      int col = colb + j*16;
#pragma unroll
      for (int r = 0; r < 4; r++){
        int row = rowb + i*16 + r;
        float v = acc[i][j][r];
        if constexpr (EP == EP_B){
          g.Cb[coff + (long)row * g.ldc + col] = f2b(v);
        } else if constexpr (EP == EP_GELU){
          g.Cb[coff + (long)row * g.ldc + col] = f2b(gelu_f(v));
        } else if constexpr (EP == EP_BIAS_GELU){
          v = gelu_f(v + g.bias[col]);
          g.Cb[coff + (long)row * g.ldc + col] = f2b(v);
        } else if constexpr (EP == EP_BIAS_RESB){
          v += g.bias[col] + b2f(g.res[(long)row * g.ldc + col]);
          g.Cb[coff + (long)row * g.ldc + col] = f2b(v);
        } else if constexpr (EP == EP_SCALE){
          g.Cb[coff + (long)row * g.ldc + col] = f2b(v * g.scale);
        } else if constexpr (EP == EP_F32){
          g.Cf[coff + (long)row * g.ldc + col] = v;
        } else { // EP_QP_GELU: rank-2 update for [x, query_pos] concat (Wh1 rows 256,257)
          v += g.qp[(long)row*2] * g.wtail[col] + g.qp[(long)row*2+1] * g.wtail[256+col];
          g.Cb[coff + (long)row * g.ldc + col] = f2b(gelu_f(v));
        }
      }
    }
  }
}

// ---------------- host ----------------

extern "C" void kernel_launch(void* const* d_in, const int* in_sizes, int n_in,
                              void* d_out, int out_size, void* d_ws, size_t ws_size,
                              hipStream_t stream){
  const float* z   = (const float*)d_in[0];
  const float* qp  = (const float*)d_in[1];
  const float* cp  = (const float*)d_in[2];
  const float* Bff = (const float*)d_in[3];
  const float* Wc1 = (const float*)d_in[4];
  const float* Wc2 = (const float*)d_in[5];
  const float* Wq  = (const float*)d_in[6];
  const float* Wkv = (const float*)d_in[7];
  const float* Wo  = (const float*)d_in[8];
  const float* bo  = (const float*)d_in[9];
  const float* Wf1 = (const float*)d_in[10];
  const float* bf1 = (const float*)d_in[11];
  const float* Wf2 = (const float*)d_in[12];
  const float* bf2 = (const float*)d_in[13];
  const float* Wh1 = (const float*)d_in[14];
  const float* Wh2 = (const float*)d_in[15];
  const float* Wh3 = (const float*)d_in[16];
  const float* bh3 = (const float*)d_in[17];
  float* out = (float*)d_out;
  (void)in_sizes; (void)n_in; (void)out_size;

  size_t mb = ws_size >> 20;
  int C;
  if      (mb >= 264) C = 1;
  else if (mb >= 168) C = 2;
  else if (mb >= 120) C = 4;
  else                C = 8;
  const int NB = 8 / C;
  const long R = (long)NB * 4096;

  char* ws = (char*)d_ws;
  const size_t MB = 1024*1024;
  u16* WqT  = (u16*)(ws + 0);
  u16* WkvT = (u16*)(ws + 512*1024);
  u16* WoT  = (u16*)(ws + 1536*1024);
  u16* Wc1T = (u16*)(ws + 2048*1024);
  u16* Wc2T = (u16*)(ws + (2048+128)*1024);
  u16* Wf1T = (u16*)(ws + (2048+256)*1024);
  u16* Wf2T = (u16*)(ws + (2048+384)*1024);
  u16* Wh1T = (u16*)(ws + (2048+512)*1024);
  u16* Wh2T = (u16*)(ws + (2048+640)*1024);
  u16* R1 = (u16*)(ws + 4*MB);    // X0b -> X2b
  u16* R2 = (u16*)(ws + 20*MB);   // Tb -> H1b
  u16* R3 = (u16*)(ws + 36*MB);   // Xb -> X3
  u16* R4 = (u16*)(ws + 52*MB);   // Zb -> H2b
  u16* kvT = (u16*)(ws + 68*MB);  // 4MB: 32 mats [e=256][d=256]
  u16* BIG1 = (u16*)(ws + 72*MB);                     // kv f32 partials -> Qb
  u16* BIG2 = (u16*)((char*)BIG1 + (size_t)NB*8*MB);  // Kt -> ATTb
  u16* BIG3 = (u16*)((char*)BIG2 + (size_t)NB*8*MB);  // Vt

  u16* X0b = R1; u16* X2b = R1;
  u16* Tb  = R2; u16* H1b = R2;
  u16* Xb  = R3;
  u16* Zb  = R4; u16* H2b = R4;

  auto G = [&](int ep, const u16* A, const u16* B, u16* Cb, float* Cf,
               const float* bias, const u16* res, const float* qq, const float* wtail,
               float scale, int M, int N, int K, int lda, int ldb, int ldc,
               int nz, int NLO, long sAh, long sAl, long sBh, long sBl, long sCh, long sCl){
    GArgs g;
    g.A=A; g.B=B; g.Cb=Cb; g.Cf=Cf; g.bias=bias; g.res=res; g.qp=qq; g.wtail=wtail;
    g.scale=scale; g.M=M; g.N=N; g.K=K; g.lda=lda; g.ldb=ldb; g.ldc=ldc; g.NLO=NLO;
    g.sAh=sAh; g.sAl=sAl; g.sBh=sBh; g.sBl=sBl; g.sCh=sCh; g.sCl=sCl;
    dim3 gr(M/128, N/128, nz); dim3 bl(256);
    switch(ep){
      case EP_B:          gemm_k<EP_B><<<gr,bl,0,stream>>>(g); break;
      case EP_GELU:       gemm_k<EP_GELU><<<gr,bl,0,stream>>>(g); break;
      case EP_BIAS_GELU:  gemm_k<EP_BIAS_GELU><<<gr,bl,0,stream>>>(g); break;
      case EP_BIAS_RESB:  gemm_k<EP_BIAS_RESB><<<gr,bl,0,stream>>>(g); break;
      case EP_SCALE:      gemm_k<EP_SCALE><<<gr,bl,0,stream>>>(g); break;
      case EP_QP_GELU:    gemm_k<EP_QP_GELU><<<gr,bl,0,stream>>>(g); break;
      case EP_F32:        gemm_k<EP_F32><<<gr,bl,0,stream>>>(g); break;
    }
  };

  // ---- weight prep + z cast
  k_cast<<<dim3(8192), dim3(256), 0, stream>>>(z, Zb);
  {
    TCArgs a;
    const float* Ws[9] = { Wq, Wkv, Wo, Wc1, Wc2, Wf1, Wf2, Wh1, Wh2 };
    u16* Wts[9] = { WqT, WkvT, WoT, Wc1T, Wc2T, Wf1T, Wf2T, Wh1T, Wh2T };
    int Ks[9] = { 256, 256, 1024, 256, 256, 256, 256, 256, 256 };
    int Ns[9] = { 1024, 2048, 256, 256, 256, 256, 256, 256, 128 };
    int off = 0;
    for (int i = 0; i < 9; i++){
      a.W[i] = Ws[i]; a.Wt[i] = Wts[i]; a.K[i] = Ks[i]; a.N[i] = Ns[i];
      a.boff[i] = off; off += Ks[i]*Ns[i]/256;
    }
    a.boff[9] = off;
    k_tcast_all<<<dim3(off), dim3(256), 0, stream>>>(a);
  }

  // ---- query trunk
  k_fourier<<<dim3(16384), dim3(256), 0, stream>>>(qp, Bff, X0b);
  G(EP_GELU, X0b, Wc1T, Tb, 0, 0,0,0,0, 1.f, 32768,256,256, 256,256,256, 1,1, 0,0,0,0,0,0);
  G(EP_B,    Tb,  Wc2T, Xb, 0, 0,0,0,0, 1.f, 32768,256,256, 256,256,256, 1,1, 0,0,0,0,0,0);

  // ---- attention arm, per batch-chunk
  for (int c = 0; c < C; c++){
    long row0 = (long)c * R;
    const u16* Zc = Zb + row0 * 256;
    // K+V fused: z@Wkv -> rot(K)/norm -> Kt, Vt  [mat][d][n]
    gemm_fuse<0><<<dim3(8, (int)(R/128)), dim3(256), 0, stream>>>(Zc, WkvT, BIG2, BIG3, cp + row0*2);
    // kv^T[e][d] = sum_n V[n,e] K[n,d], split-K 4 -> f32 partials, then reduce to bf16
    G(EP_F32, BIG3, BIG2, 0, (float*)BIG1, 0,0,0,0, 1.f,
      256,256,1024, 4096,4096,256, 4*NB*4, NB*4,
      1024,1048576, 1024,1048576, (long)NB*4*65536,65536);
    k_red<<<dim3(NB*256), dim3(256), 0, stream>>>((float*)BIG1, kvT + (long)c*NB*4*65536, (long)NB*4*65536);
    // Q = rot(x@Wq) -> [n][h*256+d]
    gemm_fuse<1><<<dim3(4, (int)(R/128)), dim3(256), 0, stream>>>(Xb + row0*256, WqT, BIG1, 0, qp + row0*2);
    // attn = q@kv * (1/nc)
    G(EP_SCALE, BIG1, kvT + (long)c*NB*4*65536, BIG2, 0, 0,0,0,0, 1.0f/4096.0f,
      4096,256,256, 1024,256,1024, NB*4,4, 4194304,256, 262144,65536, 4194304,256);
    // x2 = attn@Wo + bo + x
    G(EP_BIAS_RESB, BIG2, WoT, X2b + row0*256, 0, bo, Xb + row0*256, 0,0, 1.f,
      (int)R,256,1024, 1024,1024,256, 1,1, 0,0,0,0,0,0);
  }

  // ---- FF block + head MLP
  G(EP_BIAS_GELU, X2b, Wf1T, Tb, 0, bf1, 0,0,0, 1.f, 32768,256,256, 256,256,256, 1,1, 0,0,0,0,0,0);
  G(EP_BIAS_RESB, Tb, Wf2T, Xb, 0, bf2, X2b, 0,0, 1.f, 32768,256,256, 256,256,256, 1,1, 0,0,0,0,0,0);
  G(EP_QP_GELU, Xb, Wh1T, H1b, 0, 0,0, qp, Wh1 + 65536, 1.f, 32768,256,256, 256,256,256, 1,1, 0,0,0,0,0,0);
  G(EP_GELU, H1b, Wh2T, H2b, 0, 0,0,0,0, 1.f, 32768,128,256, 256,256,128, 1,1, 0,0,0,0,0,0);
  k_final<<<dim3(128), dim3(256), 0, stream>>>(H2b, Wh3, bh3, out);
}

// Round 6
// 526.632 us; speedup vs baseline: 1.4298x; 1.0262x over previous
//
#include <hip/hip_runtime.h>
#include <math.h>

// PointWiseDecoder2DSimple on MI355X (gfx950)
// b=8, nq=nc=4096, LATENT=256, HEADS=4, DH=256, INNER=1024.
// R6: counted-vmcnt 2-deep pipeline (T4) + both-sides LDS XOR swizzle (T2)
// in all MFMA kernels; prep kernels merged; fuse-epilogue race fixed.

typedef unsigned short u16;
typedef __attribute__((ext_vector_type(4))) float f32x4;
typedef __attribute__((ext_vector_type(8))) short s16x8;
typedef __attribute__((ext_vector_type(8))) unsigned short u16x8;
typedef __attribute__((ext_vector_type(4))) unsigned short u16x4;

#define LOG2_1E4_D64 0.20762050593046013f  // log2(10000)/64

#define VMCNT(n) do{ asm volatile("s_waitcnt vmcnt(" #n ")" ::: "memory"); \
                     __builtin_amdgcn_sched_barrier(0); }while(0)
#define BARRIER() do{ __builtin_amdgcn_s_barrier(); \
                      __builtin_amdgcn_sched_barrier(0); }while(0)

__device__ __forceinline__ u16 f2b(float f){
  union { float f; unsigned u; } v; v.f = f;
  unsigned u = v.u;
  u += 0x7FFFu + ((u >> 16) & 1u);
  return (u16)(u >> 16);
}
__device__ __forceinline__ float b2f(u16 b){
  union { unsigned u; float f; } v; v.u = ((unsigned)b) << 16; return v.f;
}
__device__ __forceinline__ float gelu_f(float x){
  return 0.5f * x * (1.0f + erff(x * 0.7071067811865475f));
}

#if __has_builtin(__builtin_amdgcn_global_load_lds)
#define HAVE_GLL 1
typedef const __attribute__((address_space(1))) void* as1cv;
typedef __attribute__((address_space(3))) void* as3v;
__device__ __forceinline__ void gload16(const void* g, void* l){
  __builtin_amdgcn_global_load_lds((as1cv)g, (as3v)l, 16, 0, 0);
}
#else
#define HAVE_GLL 0
#endif

// ---------------- merged prep: z-cast + 9 weight transposes + fourier ----------------

struct PrepArgs {
  const float* z; u16* Zb;
  const float* qp; const float* Bff; u16* X0;
  const float* W[9]; u16* Wt[9];
  int K[9]; int N[9]; int boff[10];
  int castB, tcB;
};
__global__ __launch_bounds__(256) void k_prep(PrepArgs a){
  int b = blockIdx.x, tid = threadIdx.x;
  if (b < a.castB){
    long i = (long)b * 256 + tid;
    float4 f = ((const float4*)a.z)[i];
    u16x4 o = { f2b(f.x), f2b(f.y), f2b(f.z), f2b(f.w) };
    ((u16x4*)a.Zb)[i] = o;
  } else if (b < a.castB + a.tcB){
    int bb = b - a.castB;
    int w = 0;
    while (bb >= a.boff[w+1]) w++;
    int idx = (bb - a.boff[w]) * 256 + tid;
    int K = a.K[w], N = a.N[w];
    int n = idx / K, k = idx - n * K;
    a.Wt[w][idx] = f2b(a.W[w][(long)k * N + n]);
  } else {
    int bb = b - a.castB - a.tcB;
    long r = (long)bb * 2 + (tid >> 7);
    int j = tid & 127;
    float qx = a.qp[r*2], qy = a.qp[r*2+1];
    float ff = 6.283185307179586f * (qx * a.Bff[j] + qy * a.Bff[128 + j]);
    a.X0[r*256 + j]       = f2b(sinf(ff));
    a.X0[r*256 + 128 + j] = f2b(cosf(ff));
  }
}

// split-K reduce: kvT[i] = bf16(sum_sp p[sp][i]), SPL=4
__global__ __launch_bounds__(256) void k_red(const float* __restrict__ p, u16* __restrict__ out, long stride){
  long i = (long)blockIdx.x * 256 + threadIdx.x;
  f32x4 s = ((const f32x4*)p)[i];
  s += ((const f32x4*)(p + stride))[i];
  s += ((const f32x4*)(p + 2*stride))[i];
  s += ((const f32x4*)(p + 3*stride))[i];
  u16x4 o = { f2b(s[0]), f2b(s[1]), f2b(s[2]), f2b(s[3]) };
  ((u16x4*)out)[i] = o;
}

// final head: out = H2 @ Wh3 + bh3  (N=3, K=128), fp32
__global__ __launch_bounds__(256) void k_final(const u16* __restrict__ H2, const float* __restrict__ Wh3,
                                               const float* __restrict__ bh3, float* __restrict__ out){
  long r = (long)blockIdx.x * 256 + threadIdx.x;
  float a0 = bh3[0], a1 = bh3[1], a2 = bh3[2];
  const u16x8* hrow = (const u16x8*)(H2 + r*128);
#pragma unroll
  for (int c8 = 0; c8 < 16; c8++){
    u16x8 hv = hrow[c8];
#pragma unroll
    for (int e = 0; e < 8; e++){
      float f = b2f(hv[e]);
      int k = c8*8 + e;
      a0 += f * Wh3[k*3];
      a1 += f * Wh3[k*3+1];
      a2 += f * Wh3[k*3+2];
    }
  }
  out[r*3] = a0; out[r*3+1] = a1; out[r*3+2] = a2;
}

// ---------------- fused projection GEMM: one head per block-x ----------------
// C[128x256] = A[128,256] * Bh[256,256]^T  then per MODE:
//   0: KV combined — x<4: K-head (rotary+norm+T-store), x>=4: V-head (norm+T-store)
//   1: Q — rotary + direct store [n][x*256+d]
// Pipelined staging (counted vmcnt(6), 2-deep), both-sides XOR swizzle.

template<int MODE>
__global__ __launch_bounds__(256, 2)
void gemm_fuse(const u16* __restrict__ A, const u16* __restrict__ Bw,
               u16* __restrict__ outK, u16* __restrict__ outV,
               const float* __restrict__ pos){
  __shared__ char smem[49152];
  u16* AsB = (u16*)smem;            // [2][128*32]
  u16* BsB = (u16*)(smem + 16384);  // [2][256*32]

  int tid  = threadIdx.x;
  int lane = tid & 63;
  int wave = tid >> 6;
  int wm = (wave & 1) << 6;
  int wn = (wave >> 1) << 7;
  int whalf = wave >> 1;
  int yb = blockIdx.x;
  int h  = yb & 3;
  bool isK = (MODE == 1) || (yb < 4);
  long m0 = (long)blockIdx.y * 128;

  int r15 = lane & 15;
  int cc  = lane >> 4;
  int fsw = (cc ^ ((r15 >> 1) & 3)) * 8;              // read-side swizzle
  const u16* Bh = Bw + (long)yb * 65536;

  f32x4 acc[4][8];
#pragma unroll
  for (int i = 0; i < 4; i++)
#pragma unroll
    for (int j = 0; j < 8; j++)
      acc[i][j] = f32x4{0.f, 0.f, 0.f, 0.f};

#if HAVE_GLL
  int srow  = lane >> 2;
  int scolS = ((lane & 3) ^ ((lane >> 3) & 3)) * 8;   // pre-swizzled global source
  int aRow[2], bRow[4];
  const u16 *gA[2], *gB[4];
#pragma unroll
  for (int t = 0; t < 2; t++){
    aRow[t] = (wave*2 + t) * 16;
    gA[t] = A + (m0 + aRow[t] + srow) * 256 + scolS;
  }
#pragma unroll
  for (int t = 0; t < 4; t++){
    bRow[t] = (wave*4 + t) * 16;
    gB[t] = Bh + (bRow[t] + srow) * 256 + scolS;
  }
  auto stage = [&](int buf, int kk){
    u16* ab = AsB + buf*4096;
    u16* bb = BsB + buf*8192;
#pragma unroll
    for (int t = 0; t < 2; t++) gload16(gA[t] + kk*32, ab + aRow[t]*32);
#pragma unroll
    for (int t = 0; t < 4; t++) gload16(gB[t] + kk*32, bb + bRow[t]*32);
  };
  auto compute = [&](int buf){
    const u16* ab = AsB + buf*4096;
    const u16* bb = BsB + buf*8192;
    s16x8 af[4], bf[8];
#pragma unroll
    for (int i = 0; i < 4; i++) af[i] = *(const s16x8*)&ab[(wm + i*16 + r15)*32 + fsw];
#pragma unroll
    for (int j = 0; j < 8; j++) bf[j] = *(const s16x8*)&bb[(wn + j*16 + r15)*32 + fsw];
#pragma unroll
    for (int i = 0; i < 4; i++)
#pragma unroll
      for (int j = 0; j < 8; j++)
        acc[i][j] = __builtin_amdgcn_mfma_f32_16x16x32_bf16(af[i], bf[j], acc[i][j], 0, 0, 0);
  };

  stage(0, 0);
  stage(1, 1);
  int cur = 0;
  for (int t = 0; t < 7; t++){
    VMCNT(6);
    BARRIER();
    compute(cur);
    __builtin_amdgcn_sched_barrier(0);
    BARRIER();
    if (t + 2 < 8) stage(cur, t + 2);
    cur ^= 1;
  }
  VMCNT(0);
  BARRIER();
  compute(cur);
#else
  int sm = tid >> 2, sc = tid & 3;
  for (int k0 = 0; k0 < 256; k0 += 32){
    u16x8 va  = *(const u16x8*)(A + (m0 + sm)*256 + sc*8 + k0);
    u16x8 va1 = *(const u16x8*)(A + (m0 + sm + 64)*256 + sc*8 + k0);
    u16x8 vb0 = *(const u16x8*)(Bh + (sm      )*256 + sc*8 + k0);
    u16x8 vb1 = *(const u16x8*)(Bh + (sm + 64 )*256 + sc*8 + k0);
    u16x8 vb2 = *(const u16x8*)(Bh + (sm + 128)*256 + sc*8 + k0);
    u16x8 vb3 = *(const u16x8*)(Bh + (sm + 192)*256 + sc*8 + k0);
    __syncthreads();
    *(u16x8*)&AsB[sm*32 + sc*8] = va;
    *(u16x8*)&AsB[(sm+64)*32 + sc*8] = va1;
    *(u16x8*)&BsB[sm*32 + sc*8] = vb0;
    *(u16x8*)&BsB[(sm+64)*32 + sc*8] = vb1;
    *(u16x8*)&BsB[(sm+128)*32 + sc*8] = vb2;
    *(u16x8*)&BsB[(sm+192)*32 + sc*8] = vb3;
    __syncthreads();
    s16x8 af[4], bf[8];
#pragma unroll
    for (int i = 0; i < 4; i++) af[i] = *(const s16x8*)&AsB[(wm + i*16 + r15)*32 + cc*8];
#pragma unroll
    for (int j = 0; j < 8; j++) bf[j] = *(const s16x8*)&BsB[(wn + j*16 + r15)*32 + cc*8];
#pragma unroll
    for (int i = 0; i < 4; i++)
#pragma unroll
      for (int j = 0; j < 8; j++)
        acc[i][j] = __builtin_amdgcn_mfma_f32_16x16x32_bf16(af[i], bf[j], acc[i][j], 0, 0, 0);
    __syncthreads();
  }
#endif

  // ---- rotary: pair acc[i][j] <-> acc[i][j+4]; axis = whalf
  if (isK){
    float invf4[4];
#pragma unroll
    for (int jl = 0; jl < 4; jl++)
      invf4[jl] = 1024.0f * exp2f(-(float)(jl*16 + r15) * LOG2_1E4_D64);
#pragma unroll
    for (int i = 0; i < 4; i++){
#pragma unroll
      for (int r = 0; r < 4; r++){
        long n = m0 + wm + i*16 + cc*4 + r;
        float p = pos[n*2 + whalf];
#pragma unroll
        for (int jl = 0; jl < 4; jl++){
          float a = p * invf4[jl];
          float s = __sinf(a), c = __cosf(a);
          float t0 = acc[i][jl][r], t1 = acc[i][jl+4][r];
          acc[i][jl][r]   = t0*c - t1*s;
          acc[i][jl+4][r] = t1*c + t0*s;
        }
      }
    }
  }

  if constexpr (MODE == 1){
    // Q: direct store [n][yb*256 + d]
#pragma unroll
    for (int i = 0; i < 4; i++)
#pragma unroll
      for (int j = 0; j < 8; j++)
#pragma unroll
        for (int r = 0; r < 4; r++){
          long row = m0 + wm + i*16 + cc*4 + r;
          int col = yb*256 + wn + j*16 + r15;
          outK[row*1024 + col] = f2b(acc[i][j][r]);
        }
  } else {
    // ---- inst_norm over 256 head dims, then transposed store [mat][d][n]
    u16*   TB  = (u16*)smem;               // 32KB
    float* PS1 = (float*)(smem + 32768);
    float* PS2 = (float*)(smem + 33792);

    __syncthreads();   // all waves done with staging LDS before reuse (race fix)

#pragma unroll
    for (int i = 0; i < 4; i++){
#pragma unroll
      for (int r = 0; r < 4; r++){
        float s1 = 0.f, s2 = 0.f;
#pragma unroll
        for (int j = 0; j < 8; j++){
          float v = acc[i][j][r];
          s1 += v; s2 += v*v;
        }
#pragma unroll
        for (int m = 1; m < 16; m <<= 1){
          s1 += __shfl_xor(s1, m, 64);
          s2 += __shfl_xor(s2, m, 64);
        }
        int rowid = (wave&1)*64 + i*16 + cc*4 + r;
        if (r15 == 0){ PS1[whalf*128 + rowid] = s1; PS2[whalf*128 + rowid] = s2; }
      }
    }
    __syncthreads();
#pragma unroll
    for (int i = 0; i < 4; i++){
#pragma unroll
      for (int r = 0; r < 4; r++){
        int rowid = (wave&1)*64 + i*16 + cc*4 + r;
        float s1 = PS1[rowid] + PS1[128 + rowid];
        float s2 = PS2[rowid] + PS2[128 + rowid];
        float mu  = s1 * 0.00390625f;
        float var = s2 * 0.00390625f - mu*mu;
        float inv = 1.0f / sqrtf(var + 1e-5f);
#pragma unroll
        for (int j = 0; j < 8; j++)
          acc[i][j][r] = (acc[i][j][r] - mu) * inv;
      }
    }
    __syncthreads();

    u16* outp = isK ? outK : outV;
    int bb  = (int)(m0 >> 12);
    int nn0 = (int)(m0 & 4095);
    long matbase = ((long)(bb*4 + h) * 256) * 4096;
#pragma unroll
    for (int p = 0; p < 2; p++){
      if ((wave & 1) == p){
#pragma unroll
        for (int i = 0; i < 4; i++)
#pragma unroll
          for (int j = 0; j < 8; j++)
#pragma unroll
            for (int r = 0; r < 4; r++){
              int nl = i*16 + cc*4 + r;
              int d  = wn + j*16 + r15;
              TB[nl*256 + (d ^ ((nl>>2)<<1))] = f2b(acc[i][j][r]);
            }
      }
      __syncthreads();
      {
        int n4 = (lane & 15) * 4;
        int sw = (lane & 15) << 1;
#pragma unroll
        for (int rnd = 0; rnd < 16; rnd++){
          int d = rnd*16 + wave*4 + (lane >> 4);
          u16x4 vv;
#pragma unroll
          for (int jj = 0; jj < 4; jj++) vv[jj] = TB[(n4+jj)*256 + (d ^ sw)];
          *(u16x4*)(outp + matbase + (long)d*4096 + nn0 + p*64 + n4) = vv;
        }
      }
      __syncthreads();
    }
  }
}

// ---------------- generic GEMM: C = A[M,K] * B[N,K]^T, 128x128 tile ----------------

enum { EP_B = 0, EP_GELU = 1, EP_BIAS_GELU = 2, EP_BIAS_RESB = 3, EP_SCALE = 4,
       EP_QP_GELU = 5, EP_F32 = 6 };

struct GArgs {
  const u16* A; const u16* B;
  u16* Cb; float* Cf;
  const float* bias; const u16* res; const float* qp; const float* wtail;
  float scale;
  int M, N, K, lda, ldb, ldc, NLO;
  long sAh, sAl, sBh, sBl, sCh, sCl;
};

template<int EP>
__global__ __launch_bounds__(256, 2)
void gemm_k(GArgs g){
  int z = blockIdx.z;
  int zh = z / g.NLO, zl = z - zh * g.NLO;
  const u16* A = g.A + (long)zh * g.sAh + (long)zl * g.sAl;
  const u16* B = g.B + (long)zh * g.sBh + (long)zl * g.sBl;
  long coff = (long)zh * g.sCh + (long)zl * g.sCl;

  __shared__ u16 As[2][128*32];
  __shared__ u16 Bs[2][128*32];

  int tid  = threadIdx.x;
  int lane = tid & 63;
  int wave = tid >> 6;
  int wm = (wave & 1) << 6;
  int wn = (wave >> 1) << 6;
  long m0 = (long)blockIdx.x * 128;
  long n0 = (long)blockIdx.y * 128;

  int r15 = lane & 15;
  int cc  = lane >> 4;
  int fsw = (cc ^ ((r15 >> 1) & 3)) * 8;

  f32x4 acc[4][4];
#pragma unroll
  for (int i = 0; i < 4; i++)
#pragma unroll
    for (int j = 0; j < 4; j++)
      acc[i][j] = f32x4{0.f, 0.f, 0.f, 0.f};

#if HAVE_GLL
  int srow  = lane >> 2;
  int scolS = ((lane & 3) ^ ((lane >> 3) & 3)) * 8;
  int aRow[2];
  const u16 *gA[2], *gB[2];
#pragma unroll
  for (int t = 0; t < 2; t++){
    aRow[t] = (wave*2 + t) * 16;
    gA[t] = A + (m0 + aRow[t] + srow) * g.lda + scolS;
    gB[t] = B + (n0 + aRow[t] + srow) * g.ldb + scolS;
  }
  auto stage = [&](int buf, int kk){
#pragma unroll
    for (int t = 0; t < 2; t++){
      gload16(gA[t] + kk*32, &As[buf][aRow[t]*32]);
      gload16(gB[t] + kk*32, &Bs[buf][aRow[t]*32]);
    }
  };
  auto compute = [&](int buf){
    s16x8 af[4], bf[4];
#pragma unroll
    for (int i = 0; i < 4; i++) af[i] = *(const s16x8*)&As[buf][(wm + i*16 + r15)*32 + fsw];
#pragma unroll
    for (int i = 0; i < 4; i++) bf[i] = *(const s16x8*)&Bs[buf][(wn + i*16 + r15)*32 + fsw];
#pragma unroll
    for (int i = 0; i < 4; i++)
#pragma unroll
      for (int j = 0; j < 4; j++)
        acc[i][j] = __builtin_amdgcn_mfma_f32_16x16x32_bf16(af[i], bf[j], acc[i][j], 0, 0, 0);
  };

  int nt = g.K >> 5;
  stage(0, 0);
  stage(1, 1);
  int cur = 0;
  for (int t = 0; t < nt - 1; t++){
    VMCNT(4);
    BARRIER();
    compute(cur);
    __builtin_amdgcn_sched_barrier(0);
    BARRIER();
    if (t + 2 < nt) stage(cur, t + 2);
    cur ^= 1;
  }
  VMCNT(0);
  BARRIER();
  compute(cur);
#else
  int sm  = tid >> 2;
  int sc  = tid & 3;
  for (int k0 = 0; k0 < g.K; k0 += 32){
    u16x8 va0 = *(const u16x8*)(A + (m0 + sm )*g.lda + sc*8 + k0);
    u16x8 va1 = *(const u16x8*)(A + (m0 + sm + 64)*g.lda + sc*8 + k0);
    u16x8 vb0 = *(const u16x8*)(B + (n0 + sm )*g.ldb + sc*8 + k0);
    u16x8 vb1 = *(const u16x8*)(B + (n0 + sm + 64)*g.ldb + sc*8 + k0);
    __syncthreads();
    *(u16x8*)&As[0][sm*32 + sc*8] = va0;
    *(u16x8*)&As[0][(sm+64)*32 + sc*8] = va1;
    *(u16x8*)&Bs[0][sm*32 + sc*8] = vb0;
    *(u16x8*)&Bs[0][(sm+64)*32 + sc*8] = vb1;
    __syncthreads();
    s16x8 af[4], bf[4];
#pragma unroll
    for (int i = 0; i < 4; i++) af[i] = *(const s16x8*)&As[0][(wm + i*16 + r15)*32 + cc*8];
#pragma unroll
    for (int i = 0; i < 4; i++) bf[i] = *(const s16x8*)&Bs[0][(wn + i*16 + r15)*32 + cc*8];
#pragma unroll
    for (int i = 0; i < 4; i++)
#pragma unroll
      for (int j = 0; j < 4; j++)
        acc[i][j] = __builtin_amdgcn_mfma_f32_16x16x32_bf16(af[i], bf[j], acc[i][j], 0, 0, 0);
    __syncthreads();
  }
#endif

  int colb = (int)n0 + wn + r15;
  int rowb = (int)m0 + wm + cc * 4;
#pragma unroll
  for (int i = 0; i < 4; i++){
#pragma unroll
    for (int j = 0; j < 4; j++){
      int col = colb + j*16;
#pragma unroll
      for (int r = 0; r < 4; r++){
        int row = rowb + i*16 + r;
        float v = acc[i][j][r];
        if constexpr (EP == EP_B){
          g.Cb[coff + (long)row * g.ldc + col] = f2b(v);
        } else if constexpr (EP == EP_GELU){
          g.Cb[coff + (long)row * g.ldc + col] = f2b(gelu_f(v));
        } else if constexpr (EP == EP_BIAS_GELU){
          v = gelu_f(v + g.bias[col]);
          g.Cb[coff + (long)row * g.ldc + col] = f2b(v);
        } else if constexpr (EP == EP_BIAS_RESB){
          v += g.bias[col] + b2f(g.res[(long)row * g.ldc + col]);
          g.Cb[coff + (long)row * g.ldc + col] = f2b(v);
        } else if constexpr (EP == EP_SCALE){
          g.Cb[coff + (long)row * g.ldc + col] = f2b(v * g.scale);
        } else if constexpr (EP == EP_F32){
          g.Cf[coff + (long)row * g.ldc + col] = v;
        } else { // EP_QP_GELU: rank-2 update for [x, query_pos] concat (Wh1 rows 256,257)
          v += g.qp[(long)row*2] * g.wtail[col] + g.qp[(long)row*2+1] * g.wtail[256+col];
          g.Cb[coff + (long)row * g.ldc + col] = f2b(gelu_f(v));
        }
      }
    }
  }
}

// ---------------- host ----------------

extern "C" void kernel_launch(void* const* d_in, const int* in_sizes, int n_in,
                              void* d_out, int out_size, void* d_ws, size_t ws_size,
                              hipStream_t stream){
  const float* z   = (const float*)d_in[0];
  const float* qp  = (const float*)d_in[1];
  const float* cp  = (const float*)d_in[2];
  const float* Bff = (const float*)d_in[3];
  const float* Wc1 = (const float*)d_in[4];
  const float* Wc2 = (const float*)d_in[5];
  const float* Wq  = (const float*)d_in[6];
  const float* Wkv = (const float*)d_in[7];
  const float* Wo  = (const float*)d_in[8];
  const float* bo  = (const float*)d_in[9];
  const float* Wf1 = (const float*)d_in[10];
  const float* bf1 = (const float*)d_in[11];
  const float* Wf2 = (const float*)d_in[12];
  const float* bf2 = (const float*)d_in[13];
  const float* Wh1 = (const float*)d_in[14];
  const float* Wh2 = (const float*)d_in[15];
  const float* Wh3 = (const float*)d_in[16];
  const float* bh3 = (const float*)d_in[17];
  float* out = (float*)d_out;
  (void)in_sizes; (void)n_in; (void)out_size;

  size_t mb = ws_size >> 20;
  int C;
  if      (mb >= 264) C = 1;
  else if (mb >= 168) C = 2;
  else if (mb >= 120) C = 4;
  else                C = 8;
  const int NB = 8 / C;
  const long R = (long)NB * 4096;

  char* ws = (char*)d_ws;
  const size_t MB = 1024*1024;
  u16* WqT  = (u16*)(ws + 0);
  u16* WkvT = (u16*)(ws + 512*1024);
  u16* WoT  = (u16*)(ws + 1536*1024);
  u16* Wc1T = (u16*)(ws + 2048*1024);
  u16* Wc2T = (u16*)(ws + (2048+128)*1024);
  u16* Wf1T = (u16*)(ws + (2048+256)*1024);
  u16* Wf2T = (u16*)(ws + (2048+384)*1024);
  u16* Wh1T = (u16*)(ws + (2048+512)*1024);
  u16* Wh2T = (u16*)(ws + (2048+640)*1024);
  u16* R1 = (u16*)(ws + 4*MB);    // X0b -> X2b
  u16* R2 = (u16*)(ws + 20*MB);   // Tb -> H1b
  u16* R3 = (u16*)(ws + 36*MB);   // Xb -> X3
  u16* R4 = (u16*)(ws + 52*MB);   // Zb -> H2b
  u16* kvT = (u16*)(ws + 68*MB);  // 4MB: 32 mats [e=256][d=256]
  u16* BIG1 = (u16*)(ws + 72*MB);                     // kv f32 partials -> Qb
  u16* BIG2 = (u16*)((char*)BIG1 + (size_t)NB*8*MB);  // Kt -> ATTb
  u16* BIG3 = (u16*)((char*)BIG2 + (size_t)NB*8*MB);  // Vt

  u16* X0b = R1; u16* X2b = R1;
  u16* Tb  = R2; u16* H1b = R2;
  u16* Xb  = R3;
  u16* Zb  = R4; u16* H2b = R4;

  auto G = [&](int ep, const u16* A, const u16* B, u16* Cb, float* Cf,
               const float* bias, const u16* res, const float* qq, const float* wtail,
               float scale, int M, int N, int K, int lda, int ldb, int ldc,
               int nz, int NLO, long sAh, long sAl, long sBh, long sBl, long sCh, long sCl){
    GArgs g;
    g.A=A; g.B=B; g.Cb=Cb; g.Cf=Cf; g.bias=bias; g.res=res; g.qp=qq; g.wtail=wtail;
    g.scale=scale; g.M=M; g.N=N; g.K=K; g.lda=lda; g.ldb=ldb; g.ldc=ldc; g.NLO=NLO;
    g.sAh=sAh; g.sAl=sAl; g.sBh=sBh; g.sBl=sBl; g.sCh=sCh; g.sCl=sCl;
    dim3 gr(M/128, N/128, nz); dim3 bl(256);
    switch(ep){
      case EP_B:          gemm_k<EP_B><<<gr,bl,0,stream>>>(g); break;
      case EP_GELU:       gemm_k<EP_GELU><<<gr,bl,0,stream>>>(g); break;
      case EP_BIAS_GELU:  gemm_k<EP_BIAS_GELU><<<gr,bl,0,stream>>>(g); break;
      case EP_BIAS_RESB:  gemm_k<EP_BIAS_RESB><<<gr,bl,0,stream>>>(g); break;
      case EP_SCALE:      gemm_k<EP_SCALE><<<gr,bl,0,stream>>>(g); break;
      case EP_QP_GELU:    gemm_k<EP_QP_GELU><<<gr,bl,0,stream>>>(g); break;
      case EP_F32:        gemm_k<EP_F32><<<gr,bl,0,stream>>>(g); break;
    }
  };

  // ---- merged prep: z cast + weight transposes + fourier
  {
    PrepArgs a;
    a.z = z; a.Zb = Zb; a.qp = qp; a.Bff = Bff; a.X0 = X0b;
    const float* Ws[9] = { Wq, Wkv, Wo, Wc1, Wc2, Wf1, Wf2, Wh1, Wh2 };
    u16* Wts[9] = { WqT, WkvT, WoT, Wc1T, Wc2T, Wf1T, Wf2T, Wh1T, Wh2T };
    int Ks[9] = { 256, 256, 1024, 256, 256, 256, 256, 256, 256 };
    int Ns[9] = { 1024, 2048, 256, 256, 256, 256, 256, 256, 128 };
    int off = 0;
    for (int i = 0; i < 9; i++){
      a.W[i] = Ws[i]; a.Wt[i] = Wts[i]; a.K[i] = Ks[i]; a.N[i] = Ns[i];
      a.boff[i] = off; off += Ks[i]*Ns[i]/256;
    }
    a.boff[9] = off;
    a.castB = 8192; a.tcB = off;
    k_prep<<<dim3(8192 + off + 16384), dim3(256), 0, stream>>>(a);
  }

  // ---- query trunk
  G(EP_GELU, X0b, Wc1T, Tb, 0, 0,0,0,0, 1.f, 32768,256,256, 256,256,256, 1,1, 0,0,0,0,0,0);
  G(EP_B,    Tb,  Wc2T, Xb, 0, 0,0,0,0, 1.f, 32768,256,256, 256,256,256, 1,1, 0,0,0,0,0,0);

  // ---- attention arm, per batch-chunk
  for (int c = 0; c < C; c++){
    long row0 = (long)c * R;
    const u16* Zc = Zb + row0 * 256;
    // K+V fused: z@Wkv -> rot(K)/norm -> Kt, Vt  [mat][d][n]
    gemm_fuse<0><<<dim3(8, (int)(R/128)), dim3(256), 0, stream>>>(Zc, WkvT, BIG2, BIG3, cp + row0*2);
    // kv^T[e][d] = sum_n V[n,e] K[n,d], split-K 4 -> f32 partials, then reduce to bf16
    G(EP_F32, BIG3, BIG2, 0, (float*)BIG1, 0,0,0,0, 1.f,
      256,256,1024, 4096,4096,256, 4*NB*4, NB*4,
      1024,1048576, 1024,1048576, (long)NB*4*65536,65536);
    k_red<<<dim3(NB*256), dim3(256), 0, stream>>>((float*)BIG1, kvT + (long)c*NB*4*65536, (long)NB*4*65536);
    // Q = rot(x@Wq) -> [n][h*256+d]
    gemm_fuse<1><<<dim3(4, (int)(R/128)), dim3(256), 0, stream>>>(Xb + row0*256, WqT, BIG1, 0, qp + row0*2);
    // attn = q@kv * (1/nc)
    G(EP_SCALE, BIG1, kvT + (long)c*NB*4*65536, BIG2, 0, 0,0,0,0, 1.0f/4096.0f,
      4096,256,256, 1024,256,1024, NB*4,4, 4194304,256, 262144,65536, 4194304,256);
    // x2 = attn@Wo + bo + x
    G(EP_BIAS_RESB, BIG2, WoT, X2b + row0*256, 0, bo, Xb + row0*256, 0,0, 1.f,
      (int)R,256,1024, 1024,1024,256, 1,1, 0,0,0,0,0,0);
  }

  // ---- FF block + head MLP
  G(EP_BIAS_GELU, X2b, Wf1T, Tb, 0, bf1, 0,0,0, 1.f, 32768,256,256, 256,256,256, 1,1, 0,0,0,0,0,0);
  G(EP_BIAS_RESB, Tb, Wf2T, Xb, 0, bf2, X2b, 0,0, 1.f, 32768,256,256, 256,256,256, 1,1, 0,0,0,0,0,0);
  G(EP_QP_GELU, Xb, Wh1T, H1b, 0, 0,0, qp, Wh1 + 65536, 1.f, 32768,256,256, 256,256,256, 1,1, 0,0,0,0,0,0);
  G(EP_GELU, H1b, Wh2T, H2b, 0, 0,0,0,0, 1.f, 32768,128,256, 256,256,128, 1,1, 0,0,0,0,0,0);
  k_final<<<dim3(128), dim3(256), 0, stream>>>(H2b, Wh3, bh3, out);
}